// Round 6
// baseline (781.085 us; speedup 1.0000x reference)
//
#include <hip/hip_runtime.h>
#include <stdint.h>

// ---------------------------------------------------------------------------
// MHA forward, MI355X/gfx950.
// Reference: proj(q,k,v) -> scores=QK^T/8 -> softmax (FULL row) -> mask-fill
// (post-softmax, -1e-9 where mask==0) -> PV -> out @ wout^T.   All fp32.
//
// Split-bf16 (hi/lo) MFMA everywhere: a*b ~= ahi*bhi + ahi*blo + alo*bhi.
// The -1e-9 masked-fill value is approximated by 0 (contribution ~3e-8 abs).
//
// R6: attn rewritten with SWAPPED operands (mfma(K,Q), mfma(V^T,P)) so each
// lane owns one q-row end-to-end:
//  - softmax reduce: 15 in-lane ops + 2 shfls for ALL 16 rows (was 64 shfls
//    in 4-deep chains per tile) -- the measured 85% stall was these chains.
//  - K-rows fed through kmap(cf,m)=(cf&1)*4+(m&3)+(m>>2)*8+(cf>>1)*32 so the
//    lane's P values ARE the PV B-fragment: zero LDS, zero fences, zero
//    shuffles for P assembly.
//  - launch_bounds(256,2): do NOT squeeze VGPR (R4/R5 lesson: 120->84->64
//    VGPR serialized loads, 320->417->515us).
// ---------------------------------------------------------------------------

#define BATCH  2
#define S_LEN  2048
#define DMODEL 1024
#define NH     16
#define HD     64

typedef __bf16 bf16_t;
typedef short  short8 __attribute__((ext_vector_type(8)));   // 8 x bf16 bits
typedef short  short4v __attribute__((ext_vector_type(4)));
typedef float  f32x4  __attribute__((ext_vector_type(4)));

#define AS1 __attribute__((address_space(1)))
#define AS3 __attribute__((address_space(3)))

static constexpr size_t MB = (size_t)1 << 20;
static constexpr size_t WS_REQUIRED = 112 * MB;
// Workspace layout (byte offsets). High-water: 112 MB.
//  0..48MB   : input splits qx/kx/vx (hi,lo)   [dead after projections]
//  0..16MB   : (reused) attention output O hi/lo  [written by attn]
//  16..24MB  : (reused) mask as bf16 {0,1}        [written after projections]
//  48..64MB  : weight splits wq,wk,wv,wout (hi,lo)
//  64..112MB : Q (pre-scaled 1/8), K as [B,H,S,hd]; V transposed [B,H,hd,S]
#define OFF_XHI(z)  ((size_t)(z) * 16 * MB)
#define OFF_XLO(z)  (OFF_XHI(z) + 8 * MB)
#define OFF_WHI(z)  (48 * MB + (size_t)(z) * 4 * MB)
#define OFF_WLO(z)  (OFF_WHI(z) + 2 * MB)
#define OFF_PHI(z)  (64 * MB + (size_t)(z) * 16 * MB)   // z=0:Q 1:K 2:VT
#define OFF_PLO(z)  (OFF_PHI(z) + 8 * MB)
#define OFF_OHI     ((size_t)0)
#define OFF_OLO     (8 * MB)
#define OFF_MASKB   (16 * MB)

__device__ __forceinline__ f32x4 mfma_bf16(short8 a, short8 b, f32x4 c) {
    return __builtin_amdgcn_mfma_f32_16x16x32_bf16(a, b, c, 0, 0, 0);
}

__device__ __forceinline__ short8 ld8(const bf16_t* p) {
    return *reinterpret_cast<const short8*>(p);
}

// ---------------------------------------------------------------------------
// fp32 -> (bf16 hi, bf16 lo) split conversion, vectorized float4.
// ---------------------------------------------------------------------------
__global__ void cvt_split_kernel(const float* __restrict__ x,
                                 bf16_t* __restrict__ hi, bf16_t* __restrict__ lo,
                                 int n) {
    int i = (blockIdx.x * blockDim.x + threadIdx.x) * 4;
    if (i >= n) return;
    const float4 v = *reinterpret_cast<const float4*>(x + i);
    float s[4] = {v.x, v.y, v.z, v.w};
    ushort hbits[4], lbits[4];
#pragma unroll
    for (int j = 0; j < 4; j++) {
        bf16_t hh = (bf16_t)s[j];
        bf16_t ll = (bf16_t)(s[j] - (float)hh);
        hbits[j] = __builtin_bit_cast(ushort, hh);
        lbits[j] = __builtin_bit_cast(ushort, ll);
    }
    *reinterpret_cast<ushort4*>(hi + i) = ushort4{hbits[0], hbits[1], hbits[2], hbits[3]};
    *reinterpret_cast<ushort4*>(lo + i) = ushort4{lbits[0], lbits[1], lbits[2], lbits[3]};
}

// mask int32 -> bf16 {0,1}
__global__ void cvt_mask_kernel(const int* __restrict__ m, bf16_t* __restrict__ mb, int n) {
    int i = (blockIdx.x * blockDim.x + threadIdx.x) * 4;
    if (i >= n) return;
    const int4 v = *reinterpret_cast<const int4*>(m + i);
    int s[4] = {v.x, v.y, v.z, v.w};
    ushort b[4];
#pragma unroll
    for (int j = 0; j < 4; j++) {
        bf16_t t = (bf16_t)(s[j] ? 1.0f : 0.0f);
        b[j] = __builtin_bit_cast(ushort, t);
    }
    *reinterpret_cast<ushort4*>(mb + i) = ushort4{b[0], b[1], b[2], b[3]};
}

// ---------------------------------------------------------------------------
// Split-bf16 GEMM, C = A @ B^T (both operands K-contiguous), K=1024 done as
// 3 segments {(Ahi,Bhi),(Ahi,Blo),(Alo,Bhi)}.  128x128 tile, BK=32,
// 256 threads = 4 waves (2x2), each wave 64x64 = 4x4 16x16x32 frags.
// FINAL=0: grid.z picks q/k/v; epilogue writes head-split hi/lo (Q scaled
//          1/8; V transposed).  FINAL=1: output projection, fp32 -> d_out.
// ---------------------------------------------------------------------------
template <int FINAL>
__global__ __launch_bounds__(256, 2) void gemm_split_kernel(char* __restrict__ ws,
                                                            float* __restrict__ fout) {
    __shared__ __align__(16) bf16_t As[128 * 32];
    __shared__ __align__(16) bf16_t Bs[128 * 32];

    const int z = FINAL ? 3 : blockIdx.z;
    const bf16_t* Ahi = FINAL ? (const bf16_t*)(ws + OFF_OHI) : (const bf16_t*)(ws + OFF_XHI(z));
    const bf16_t* Alo = FINAL ? (const bf16_t*)(ws + OFF_OLO) : (const bf16_t*)(ws + OFF_XLO(z));
    const bf16_t* Bhi = (const bf16_t*)(ws + OFF_WHI(z));
    const bf16_t* Blo = (const bf16_t*)(ws + OFF_WLO(z));
    bf16_t* Ohi = FINAL ? nullptr : (bf16_t*)(ws + OFF_PHI(z));
    bf16_t* Olo = FINAL ? nullptr : (bf16_t*)(ws + OFF_PLO(z));
    const float scale = (!FINAL && z == 0) ? 0.125f : 1.0f;  // 1/sqrt(hd) folded into Q

    const int tid = threadIdx.x;
    const int lane = tid & 63, w = tid >> 6;
    const int wr = w >> 1, wc = w & 1;
    const int fr = lane & 15, fg = lane >> 4;
    const int m0 = blockIdx.x * 128, n0 = blockIdx.y * 128;
    const int K = 1024;

    const bf16_t* Aseg[3] = {Ahi, Ahi, Alo};
    const bf16_t* Bseg[3] = {Bhi, Blo, Bhi};

    f32x4 acc[4][4];
#pragma unroll
    for (int i = 0; i < 4; i++)
#pragma unroll
        for (int j = 0; j < 4; j++) acc[i][j] = f32x4{0.f, 0.f, 0.f, 0.f};

    AS3 bf16_t* asA = (AS3 bf16_t*)As;
    AS3 bf16_t* asB = (AS3 bf16_t*)Bs;

#pragma unroll 1
    for (int seg = 0; seg < 3; ++seg) {
        const bf16_t* Ab = Aseg[seg];
        const bf16_t* Bb = Bseg[seg];
#pragma unroll 1
        for (int ks = 0; ks < K; ks += 32) {
            __syncthreads();  // previous compute done before restaging
#pragma unroll
            for (int i = 0; i < 2; i++) {
                // chunk c covers 16B: LDS byte c*16; global row c/4, 16B col (c&3)*16
                const int c = i * 256 + tid;
                const int row = c >> 2;
                const int ce = (c & 3) * 8;  // element offset within row
                __builtin_amdgcn_global_load_lds((const AS1 void*)(Ab + (size_t)(m0 + row) * K + ks + ce),
                                                 (AS3 void*)(asA + (size_t)(i * 256 + w * 64) * 8),
                                                 16, 0, 0);
                __builtin_amdgcn_global_load_lds((const AS1 void*)(Bb + (size_t)(n0 + row) * K + ks + ce),
                                                 (AS3 void*)(asB + (size_t)(i * 256 + w * 64) * 8),
                                                 16, 0, 0);
            }
            __syncthreads();  // staging visible (syncthreads drains vmcnt)

            short8 af[4], bfr[4];
#pragma unroll
            for (int i = 0; i < 4; i++) {
                af[i]  = ld8(&As[(wr * 64 + i * 16 + fr) * 32 + fg * 8]);
                bfr[i] = ld8(&Bs[(wc * 64 + i * 16 + fr) * 32 + fg * 8]);
            }
#pragma unroll
            for (int i = 0; i < 4; i++)
#pragma unroll
                for (int j = 0; j < 4; j++)
                    acc[i][j] = mfma_bf16(af[i], bfr[j], acc[i][j]);
        }
    }

    // Epilogue. C/D frag: col = lane&15, row = (lane>>4)*4 + reg  [HW-verified]
#pragma unroll
    for (int i = 0; i < 4; i++) {
#pragma unroll
        for (int j = 0; j < 4; j++) {
            const int ncol = n0 + wc * 64 + j * 16 + fr;
#pragma unroll
            for (int r = 0; r < 4; r++) {
                const int m = m0 + wr * 64 + i * 16 + fg * 4 + r;
                const float val = acc[i][j][r] * scale;
                if (FINAL) {
                    fout[(size_t)m * DMODEL + ncol] = val;
                } else {
                    const bf16_t h = (bf16_t)val;
                    const bf16_t l = (bf16_t)(val - (float)h);
                    const int b = m >> 11, s = m & (S_LEN - 1);
                    const int hh = ncol >> 6, d = ncol & (HD - 1);
                    size_t idx;
                    if (z == 2) idx = ((size_t)(b * NH + hh) * HD + d) * S_LEN + s;      // VT [B,H,hd,S]
                    else        idx = ((size_t)(b * NH + hh) * S_LEN + s) * HD + d;      // [B,H,S,hd]
                    Ohi[idx] = h;
                    Olo[idx] = l;
                }
            }
        }
    }
}

// ---------------------------------------------------------------------------
// Flash attention, swapped-operand, LDS-free.  Grid: (S/64, B*H), 256 thr =
// 4 independent waves x 16 q-rows.  Lane (fr,fg) owns q-row fr of its wave.
//
// QK^T swapped: sacc[cf] = mfma(A=Kfrag, B=Qfrag) -> D[col=fr=q][row=k'].
// K rows permuted per tile: k = k0 + (cf&1)*4 + r + fg*8 + (cf>>1)*32, so
// the lane's 16 P values are exactly the two contiguous k-quads of each PV
// B-fragment (k = kc2*32 + fg*8 + j): pure in-register repack, no LDS.
// PV swapped: acco[df] = mfma(A=VTfrag, B=Pfrag) -> D[col=fr=q][row=d].
// Softmax: 15 in-lane ops + shfl_xor(16,32) reduces all 16 q-rows at once;
// alpha/l are per-lane scalars.
// ---------------------------------------------------------------------------
__global__ __launch_bounds__(256, 2) void attn_kernel(char* __restrict__ ws) {
    const bf16_t* Qhi = (const bf16_t*)(ws + OFF_PHI(0));
    const bf16_t* Qlo = (const bf16_t*)(ws + OFF_PLO(0));
    const bf16_t* Khi = (const bf16_t*)(ws + OFF_PHI(1));
    const bf16_t* Klo = (const bf16_t*)(ws + OFF_PLO(1));
    const bf16_t* Vhi = (const bf16_t*)(ws + OFF_PHI(2));
    const bf16_t* Vlo = (const bf16_t*)(ws + OFF_PLO(2));
    const bf16_t* Mb  = (const bf16_t*)(ws + OFF_MASKB);
    bf16_t* Ohi = (bf16_t*)(ws + OFF_OHI);
    bf16_t* Olo = (bf16_t*)(ws + OFF_OLO);

    const int tid = threadIdx.x, lane = tid & 63, w = tid >> 6;
    const int fr = lane & 15, fg = lane >> 4;
    const int bh = blockIdx.y;
    const int q0 = blockIdx.x * 64;
    const int qrow = q0 + w * 16 + fr;          // this lane's q-row
    const size_t qkBase = (size_t)bh * S_LEN * HD;
    const size_t vtBase = (size_t)bh * HD * S_LEN;

    // Q fragments (B-operand): Q[q=fr][hd contig 8], pre-scaled by 1/8
    short8 qh[2], ql[2];
#pragma unroll
    for (int kc = 0; kc < 2; kc++) {
        const size_t off = qkBase + (size_t)qrow * HD + kc * 32 + fg * 8;
        qh[kc] = ld8(Qhi + off);
        ql[kc] = ld8(Qlo + off);
    }

    f32x4 acco[4];                               // O^T: row d=df*16+fg*4+r, col q=fr
#pragma unroll
    for (int df = 0; df < 4; df++) acco[df] = f32x4{0.f, 0.f, 0.f, 0.f};
    float mrun = -__builtin_inff(), lrun = 0.f;  // per-lane scalars (own q-row)

    const size_t mrowBase = (size_t)qrow * S_LEN;

#pragma unroll 1
    for (int k0 = 0; k0 < S_LEN; k0 += 64) {
        // ---- mask for this lane's k-set: 4 contiguous bf16 per cf (8B loads)
        float mv[4][4];
#pragma unroll
        for (int cf = 0; cf < 4; cf++) {
            const int kbase = k0 + (cf & 1) * 4 + fg * 8 + (cf >> 1) * 32;
            const short4v mq = *reinterpret_cast<const short4v*>(Mb + mrowBase + kbase);
#pragma unroll
            for (int r = 0; r < 4; r++)
                mv[cf][r] = (float)__builtin_bit_cast(bf16_t, (ushort)mq[r]);
        }

        // ---- scores (swapped): sacc[cf][r] = S[q=fr][k0+(cf&1)*4+r+fg*8+(cf>>1)*32]
        f32x4 sacc[4];
#pragma unroll
        for (int cf = 0; cf < 4; cf++) sacc[cf] = f32x4{0.f, 0.f, 0.f, 0.f};
#pragma unroll
        for (int cf = 0; cf < 4; cf++) {
            // A-frag row m=fr -> K row k0 + kmap(cf, fr)
            const int krow = k0 + (cf & 1) * 4 + (fr & 3) + ((fr >> 2) & 3) * 8 + (cf >> 1) * 32;
#pragma unroll
            for (int kc = 0; kc < 2; kc++) {
                const size_t off = qkBase + (size_t)krow * HD + kc * 32 + fg * 8;
                const short8 kh = ld8(Khi + off);
                const short8 kl = ld8(Klo + off);
                sacc[cf] = mfma_bf16(kh, qh[kc], sacc[cf]);
                sacc[cf] = mfma_bf16(kl, qh[kc], sacc[cf]);
                sacc[cf] = mfma_bf16(kh, ql[kc], sacc[cf]);
            }
        }

        // ---- online softmax, all 16 q-rows of the wave at once (in-lane + 2 shfl)
        float mx = sacc[0][0];
#pragma unroll
        for (int cf = 0; cf < 4; cf++)
#pragma unroll
            for (int r = 0; r < 4; r++) mx = fmaxf(mx, sacc[cf][r]);
        mx = fmaxf(mx, __shfl_xor(mx, 16, 64));
        mx = fmaxf(mx, __shfl_xor(mx, 32, 64));
        const float mnew = fmaxf(mrun, mx);
        const float alpha = __expf(mrun - mnew);
        mrun = mnew;

        float p[4][4], psum = 0.f;
#pragma unroll
        for (int cf = 0; cf < 4; cf++)
#pragma unroll
            for (int r = 0; r < 4; r++) {
                p[cf][r] = __expf(sacc[cf][r] - mnew);
                psum += p[cf][r];
            }
        psum += __shfl_xor(psum, 16, 64);
        psum += __shfl_xor(psum, 32, 64);
        lrun = lrun * alpha + psum;
#pragma unroll
        for (int df = 0; df < 4; df++) acco[df] *= alpha;

        // ---- masked P -> hi/lo PV B-fragments, pure in-register
        short8 phi[2], plo[2];
#pragma unroll
        for (int kc2 = 0; kc2 < 2; kc2++) {
#pragma unroll
            for (int j = 0; j < 8; j++) {
                const int cf = kc2 * 2 + (j >> 2), r = j & 3;
                const float pm = p[cf][r] * mv[cf][r];
                const bf16_t h = (bf16_t)pm;
                const bf16_t l = (bf16_t)(pm - (float)h);
                phi[kc2][j] = __builtin_bit_cast(short, h);
                plo[kc2][j] = __builtin_bit_cast(short, l);
            }
        }

        // ---- PV (swapped): acco[df] += VT-frag x P-frag
#pragma unroll
        for (int kc2 = 0; kc2 < 2; kc2++) {
#pragma unroll
            for (int df = 0; df < 4; df++) {
                const size_t voff = vtBase + (size_t)(df * 16 + fr) * S_LEN + k0 + kc2 * 32 + fg * 8;
                const short8 vh = ld8(Vhi + voff);
                const short8 vl = ld8(Vlo + voff);
                acco[df] = mfma_bf16(vh, phi[kc2], acco[df]);
                acco[df] = mfma_bf16(vl, phi[kc2], acco[df]);
                acco[df] = mfma_bf16(vh, plo[kc2], acco[df]);
            }
        }
    }

    // ---- epilogue: normalize (per-lane), split hi/lo, store O as [B,S,D]
    const int b = bh >> 4, hh = bh & (NH - 1);
    const float inv = 1.0f / lrun;
    const size_t obase = ((size_t)b * S_LEN + qrow) * DMODEL + hh * HD;
#pragma unroll
    for (int df = 0; df < 4; df++) {
#pragma unroll
        for (int r = 0; r < 4; r++) {
            const int d = df * 16 + fg * 4 + r;
            const float o = acco[df][r] * inv;
            const bf16_t h = (bf16_t)o;
            Ohi[obase + d] = h;
            Olo[obase + d] = (bf16_t)(o - (float)h);
        }
    }
}

// ---------------------------------------------------------------------------
extern "C" void kernel_launch(void* const* d_in, const int* in_sizes, int n_in,
                              void* d_out, int out_size, void* d_ws, size_t ws_size,
                              hipStream_t stream) {
    (void)in_sizes; (void)n_in; (void)out_size;
    if (ws_size < WS_REQUIRED) return;  // clean incorrect-output signal, not an OOB crash

    const float* q    = (const float*)d_in[0];
    const float* k    = (const float*)d_in[1];
    const float* v    = (const float*)d_in[2];
    const int*   mask = (const int*)  d_in[3];
    const float* wq   = (const float*)d_in[4];
    const float* wk   = (const float*)d_in[5];
    const float* wv   = (const float*)d_in[6];
    const float* wout = (const float*)d_in[7];
    char* ws = (char*)d_ws;
    float* out = (float*)d_out;

    const size_t nX = (size_t)BATCH * S_LEN * DMODEL;  // 4,194,304
    const size_t nW = (size_t)DMODEL * DMODEL;         // 1,048,576
    const size_t nM = (size_t)S_LEN * S_LEN;           // 4,194,304
    const dim3 blk(256);

    // fp32 -> hi/lo splits
    cvt_split_kernel<<<dim3(nX / 1024), blk, 0, stream>>>(q, (bf16_t*)(ws + OFF_XHI(0)), (bf16_t*)(ws + OFF_XLO(0)), (int)nX);
    cvt_split_kernel<<<dim3(nX / 1024), blk, 0, stream>>>(k, (bf16_t*)(ws + OFF_XHI(1)), (bf16_t*)(ws + OFF_XLO(1)), (int)nX);
    cvt_split_kernel<<<dim3(nX / 1024), blk, 0, stream>>>(v, (bf16_t*)(ws + OFF_XHI(2)), (bf16_t*)(ws + OFF_XLO(2)), (int)nX);
    cvt_split_kernel<<<dim3(nW / 1024), blk, 0, stream>>>(wq,   (bf16_t*)(ws + OFF_WHI(0)), (bf16_t*)(ws + OFF_WLO(0)), (int)nW);
    cvt_split_kernel<<<dim3(nW / 1024), blk, 0, stream>>>(wk,   (bf16_t*)(ws + OFF_WHI(1)), (bf16_t*)(ws + OFF_WLO(1)), (int)nW);
    cvt_split_kernel<<<dim3(nW / 1024), blk, 0, stream>>>(wv,   (bf16_t*)(ws + OFF_WHI(2)), (bf16_t*)(ws + OFF_WLO(2)), (int)nW);
    cvt_split_kernel<<<dim3(nW / 1024), blk, 0, stream>>>(wout, (bf16_t*)(ws + OFF_WHI(3)), (bf16_t*)(ws + OFF_WLO(3)), (int)nW);

    // q/k/v projections (z = 0/1/2), head-split epilogues
    gemm_split_kernel<0><<<dim3(32, 8, 3), blk, 0, stream>>>(ws, nullptr);

    // mask -> bf16 {0,1} into region freed by the input splits (stream-ordered
    // after the projections, which are the last readers of that region)
    cvt_mask_kernel<<<dim3(nM / 1024), blk, 0, stream>>>(mask, (bf16_t*)(ws + OFF_MASKB), (int)nM);

    // flash attention, swapped-operand, LDS-free (1024 blocks)
    attn_kernel<<<dim3(S_LEN / 64, BATCH * NH), blk, 0, stream>>>(ws);

    // output projection -> d_out (fp32)
    gemm_split_kernel<1><<<dim3(32, 8, 1), blk, 0, stream>>>(ws, out);
}

// Round 7
// 485.586 us; speedup vs baseline: 1.6085x; 1.6085x over previous
//
#include <hip/hip_runtime.h>
#include <stdint.h>

// ---------------------------------------------------------------------------
// MHA forward, MI355X/gfx950.
// Reference: proj(q,k,v) -> scores=QK^T/8 -> softmax (FULL row) -> mask-fill
// (post-softmax, -1e-9 where mask==0) -> PV -> out @ wout^T.   All fp32.
//
// Split-bf16 (hi/lo) MFMA everywhere: a*b ~= ahi*bhi + ahi*blo + alo*bhi.
// The -1e-9 masked-fill value is approximated by 0 (contribution ~3e-8 abs).
//
// R7: R3-R6 showed attn is bound by scattered VMEM request count (runtime
// tracks wave-load count: 320us @2048 waves vs 510us @4096 waves, invariant
// to occupancy/LDS/shuffles).  Fix: cooperative K/V staging shared by all 4
// waves, global_load_lds(16B) into MFMA-FRAGMENT-ORDERED LDS (the kmap
// permutation is baked into the staging SOURCE address; LDS dest stays
// linear per the wave-uniform-base rule).  ds_read_b128 is then wave-linear:
// zero bank conflicts, no swizzle.  Mask: 2x16B loads (was 4x8B).
// Softmax/PV keep R6's swapped-operand in-register pipeline.
// ---------------------------------------------------------------------------

#define BATCH  2
#define S_LEN  2048
#define DMODEL 1024
#define NH     16
#define HD     64

typedef __bf16 bf16_t;
typedef short  short8 __attribute__((ext_vector_type(8)));   // 8 x bf16 bits
typedef float  f32x4  __attribute__((ext_vector_type(4)));

#define AS1 __attribute__((address_space(1)))
#define AS3 __attribute__((address_space(3)))

static constexpr size_t MB = (size_t)1 << 20;
static constexpr size_t WS_REQUIRED = 112 * MB;
// Workspace layout (byte offsets). High-water: 112 MB.
//  0..48MB   : input splits qx/kx/vx (hi,lo)   [dead after projections]
//  0..16MB   : (reused) attention output O hi/lo  [written by attn]
//  16..24MB  : (reused) mask as bf16 {0,1}        [written after projections]
//  48..64MB  : weight splits wq,wk,wv,wout (hi,lo)
//  64..112MB : Q (pre-scaled 1/8), K as [B,H,S,hd]; V transposed [B,H,hd,S]
#define OFF_XHI(z)  ((size_t)(z) * 16 * MB)
#define OFF_XLO(z)  (OFF_XHI(z) + 8 * MB)
#define OFF_WHI(z)  (48 * MB + (size_t)(z) * 4 * MB)
#define OFF_WLO(z)  (OFF_WHI(z) + 2 * MB)
#define OFF_PHI(z)  (64 * MB + (size_t)(z) * 16 * MB)   // z=0:Q 1:K 2:VT
#define OFF_PLO(z)  (OFF_PHI(z) + 8 * MB)
#define OFF_OHI     ((size_t)0)
#define OFF_OLO     (8 * MB)
#define OFF_MASKB   (16 * MB)

__device__ __forceinline__ f32x4 mfma_bf16(short8 a, short8 b, f32x4 c) {
    return __builtin_amdgcn_mfma_f32_16x16x32_bf16(a, b, c, 0, 0, 0);
}

__device__ __forceinline__ short8 ld8(const bf16_t* p) {
    return *reinterpret_cast<const short8*>(p);
}

// ---------------------------------------------------------------------------
// fp32 -> (bf16 hi, bf16 lo) split conversion, vectorized float4.
// ---------------------------------------------------------------------------
__global__ void cvt_split_kernel(const float* __restrict__ x,
                                 bf16_t* __restrict__ hi, bf16_t* __restrict__ lo,
                                 int n) {
    int i = (blockIdx.x * blockDim.x + threadIdx.x) * 4;
    if (i >= n) return;
    const float4 v = *reinterpret_cast<const float4*>(x + i);
    float s[4] = {v.x, v.y, v.z, v.w};
    ushort hbits[4], lbits[4];
#pragma unroll
    for (int j = 0; j < 4; j++) {
        bf16_t hh = (bf16_t)s[j];
        bf16_t ll = (bf16_t)(s[j] - (float)hh);
        hbits[j] = __builtin_bit_cast(ushort, hh);
        lbits[j] = __builtin_bit_cast(ushort, ll);
    }
    *reinterpret_cast<ushort4*>(hi + i) = ushort4{hbits[0], hbits[1], hbits[2], hbits[3]};
    *reinterpret_cast<ushort4*>(lo + i) = ushort4{lbits[0], lbits[1], lbits[2], lbits[3]};
}

// mask int32 -> bf16 {0,1}
__global__ void cvt_mask_kernel(const int* __restrict__ m, bf16_t* __restrict__ mb, int n) {
    int i = (blockIdx.x * blockDim.x + threadIdx.x) * 4;
    if (i >= n) return;
    const int4 v = *reinterpret_cast<const int4*>(m + i);
    int s[4] = {v.x, v.y, v.z, v.w};
    ushort b[4];
#pragma unroll
    for (int j = 0; j < 4; j++) {
        bf16_t t = (bf16_t)(s[j] ? 1.0f : 0.0f);
        b[j] = __builtin_bit_cast(ushort, t);
    }
    *reinterpret_cast<ushort4*>(mb + i) = ushort4{b[0], b[1], b[2], b[3]};
}

// ---------------------------------------------------------------------------
// Split-bf16 GEMM, C = A @ B^T (both operands K-contiguous), K=1024 done as
// 3 segments {(Ahi,Bhi),(Ahi,Blo),(Alo,Bhi)}.  128x128 tile, BK=32,
// 256 threads = 4 waves (2x2), each wave 64x64 = 4x4 16x16x32 frags.
// FINAL=0: grid.z picks q/k/v; epilogue writes head-split hi/lo (Q scaled
//          1/8; V transposed).  FINAL=1: output projection, fp32 -> d_out.
// ---------------------------------------------------------------------------
template <int FINAL>
__global__ __launch_bounds__(256, 2) void gemm_split_kernel(char* __restrict__ ws,
                                                            float* __restrict__ fout) {
    __shared__ __align__(16) bf16_t As[128 * 32];
    __shared__ __align__(16) bf16_t Bs[128 * 32];

    const int z = FINAL ? 3 : blockIdx.z;
    const bf16_t* Ahi = FINAL ? (const bf16_t*)(ws + OFF_OHI) : (const bf16_t*)(ws + OFF_XHI(z));
    const bf16_t* Alo = FINAL ? (const bf16_t*)(ws + OFF_OLO) : (const bf16_t*)(ws + OFF_XLO(z));
    const bf16_t* Bhi = (const bf16_t*)(ws + OFF_WHI(z));
    const bf16_t* Blo = (const bf16_t*)(ws + OFF_WLO(z));
    bf16_t* Ohi = FINAL ? nullptr : (bf16_t*)(ws + OFF_PHI(z));
    bf16_t* Olo = FINAL ? nullptr : (bf16_t*)(ws + OFF_PLO(z));
    const float scale = (!FINAL && z == 0) ? 0.125f : 1.0f;  // 1/sqrt(hd) folded into Q

    const int tid = threadIdx.x;
    const int lane = tid & 63, w = tid >> 6;
    const int wr = w >> 1, wc = w & 1;
    const int fr = lane & 15, fg = lane >> 4;
    const int m0 = blockIdx.x * 128, n0 = blockIdx.y * 128;
    const int K = 1024;

    const bf16_t* Aseg[3] = {Ahi, Ahi, Alo};
    const bf16_t* Bseg[3] = {Bhi, Blo, Bhi};

    f32x4 acc[4][4];
#pragma unroll
    for (int i = 0; i < 4; i++)
#pragma unroll
        for (int j = 0; j < 4; j++) acc[i][j] = f32x4{0.f, 0.f, 0.f, 0.f};

    AS3 bf16_t* asA = (AS3 bf16_t*)As;
    AS3 bf16_t* asB = (AS3 bf16_t*)Bs;

#pragma unroll 1
    for (int seg = 0; seg < 3; ++seg) {
        const bf16_t* Ab = Aseg[seg];
        const bf16_t* Bb = Bseg[seg];
#pragma unroll 1
        for (int ks = 0; ks < K; ks += 32) {
            __syncthreads();  // previous compute done before restaging
#pragma unroll
            for (int i = 0; i < 2; i++) {
                // chunk c covers 16B: LDS byte c*16; global row c/4, 16B col (c&3)*16
                const int c = i * 256 + tid;
                const int row = c >> 2;
                const int ce = (c & 3) * 8;  // element offset within row
                __builtin_amdgcn_global_load_lds((const AS1 void*)(Ab + (size_t)(m0 + row) * K + ks + ce),
                                                 (AS3 void*)(asA + (size_t)(i * 256 + w * 64) * 8),
                                                 16, 0, 0);
                __builtin_amdgcn_global_load_lds((const AS1 void*)(Bb + (size_t)(n0 + row) * K + ks + ce),
                                                 (AS3 void*)(asB + (size_t)(i * 256 + w * 64) * 8),
                                                 16, 0, 0);
            }
            __syncthreads();  // staging visible (syncthreads drains vmcnt)

            short8 af[4], bfr[4];
#pragma unroll
            for (int i = 0; i < 4; i++) {
                af[i]  = ld8(&As[(wr * 64 + i * 16 + fr) * 32 + fg * 8]);
                bfr[i] = ld8(&Bs[(wc * 64 + i * 16 + fr) * 32 + fg * 8]);
            }
#pragma unroll
            for (int i = 0; i < 4; i++)
#pragma unroll
                for (int j = 0; j < 4; j++)
                    acc[i][j] = mfma_bf16(af[i], bfr[j], acc[i][j]);
        }
    }

    // Epilogue. C/D frag: col = lane&15, row = (lane>>4)*4 + reg  [HW-verified]
#pragma unroll
    for (int i = 0; i < 4; i++) {
#pragma unroll
        for (int j = 0; j < 4; j++) {
            const int ncol = n0 + wc * 64 + j * 16 + fr;
#pragma unroll
            for (int r = 0; r < 4; r++) {
                const int m = m0 + wr * 64 + i * 16 + fg * 4 + r;
                const float val = acc[i][j][r] * scale;
                if (FINAL) {
                    fout[(size_t)m * DMODEL + ncol] = val;
                } else {
                    const bf16_t h = (bf16_t)val;
                    const bf16_t l = (bf16_t)(val - (float)h);
                    const int b = m >> 11, s = m & (S_LEN - 1);
                    const int hh = ncol >> 6, d = ncol & (HD - 1);
                    size_t idx;
                    if (z == 2) idx = ((size_t)(b * NH + hh) * HD + d) * S_LEN + s;      // VT [B,H,hd,S]
                    else        idx = ((size_t)(b * NH + hh) * S_LEN + s) * HD + d;      // [B,H,S,hd]
                    Ohi[idx] = h;
                    Olo[idx] = l;
                }
            }
        }
    }
}

// ---------------------------------------------------------------------------
// Flash attention, swapped-operand, LDS-staged.  Grid: (S/64, B*H), 256 thr
// = 4 waves x 16 q-rows; lane (fr,fg) owns q-row w*16+fr.
//
// Per 64-k tile, the block cooperatively stages K hi/lo and V^T hi/lo into
// MFMA-FRAGMENT-ORDERED LDS: slot (frag f, lane l) holds the 16B that lane
// l reads for fragment f.  The QK^T k-row permutation
//   kmap(cf,fr) = (cf&1)*4 + (fr&3) + (fr>>2)*8 + (cf>>1)*32
// is applied on the staging SOURCE address (global src is per-lane; LDS dest
// is wave-uniform+lane*16 = linear).  Compute reads are wave-linear
// ds_read_b128: zero bank conflicts.
//
// QK^T swapped: sacc[cf] = mfma(A=Kfrag, B=Qfrag) -> D[col=fr=q][row=k'].
// The lane's 16 P values are exactly the two PV B-fragments (k = kc2*32 +
// fg*8 + j): pure in-register repack.  PV swapped: acco[df] =
// mfma(A=VTfrag, B=Pfrag).  Softmax: in-lane + 2 shfls for all 16 q-rows.
// ---------------------------------------------------------------------------
__global__ __launch_bounds__(256, 2) void attn_kernel(char* __restrict__ ws) {
    // fragment-ordered tiles: [frag 0..7][lane 0..63][8 bf16] = 8KB each
    __shared__ __align__(16) bf16_t KsH[8 * 64 * 8];
    __shared__ __align__(16) bf16_t KsL[8 * 64 * 8];
    __shared__ __align__(16) bf16_t VsH[8 * 64 * 8];
    __shared__ __align__(16) bf16_t VsL[8 * 64 * 8];

    const bf16_t* Qhi = (const bf16_t*)(ws + OFF_PHI(0));
    const bf16_t* Qlo = (const bf16_t*)(ws + OFF_PLO(0));
    const bf16_t* Khi = (const bf16_t*)(ws + OFF_PHI(1));
    const bf16_t* Klo = (const bf16_t*)(ws + OFF_PLO(1));
    const bf16_t* Vhi = (const bf16_t*)(ws + OFF_PHI(2));
    const bf16_t* Vlo = (const bf16_t*)(ws + OFF_PLO(2));
    const bf16_t* Mb  = (const bf16_t*)(ws + OFF_MASKB);
    bf16_t* Ohi = (bf16_t*)(ws + OFF_OHI);
    bf16_t* Olo = (bf16_t*)(ws + OFF_OLO);

    const int tid = threadIdx.x, lane = tid & 63, w = tid >> 6;
    const int fr = lane & 15, fg = lane >> 4;
    const int bh = blockIdx.y;
    const int q0 = blockIdx.x * 64;
    const int qrow = q0 + w * 16 + fr;          // this lane's q-row
    const size_t qkBase = (size_t)bh * S_LEN * HD;
    const size_t vtBase = (size_t)bh * HD * S_LEN;

    // Staging source offsets for this thread's two slots (s = i*256 + tid):
    // slot s -> lane l=s&63, frag f=(s>>6)&7.  K: f=cf*2+kc, row kmap(cf,l&15),
    // col kc*32+(l>>4)*8.  V: f=df*2+kc2, row df*16+(l&15), col kc2*32+(l>>4)*8.
    size_t kSrc[2], vSrc[2];
#pragma unroll
    for (int i = 0; i < 2; i++) {
        const int s = i * 256 + tid;
        const int l = s & 63, f = (s >> 6) & 7;
        const int sfr = l & 15, sfg = l >> 4;
        const int cf = f >> 1, kc = f & 1;
        const int r = (cf & 1) * 4 + (sfr & 3) + (sfr >> 2) * 8 + (cf >> 1) * 32;
        kSrc[i] = qkBase + (size_t)r * HD + kc * 32 + sfg * 8;          // + k0*HD
        vSrc[i] = vtBase + (size_t)((f >> 1) * 16 + sfr) * S_LEN + (f & 1) * 32 + sfg * 8;  // + k0
    }

    AS3 bf16_t* asKH = (AS3 bf16_t*)KsH;
    AS3 bf16_t* asKL = (AS3 bf16_t*)KsL;
    AS3 bf16_t* asVH = (AS3 bf16_t*)VsH;
    AS3 bf16_t* asVL = (AS3 bf16_t*)VsL;

    // Q fragments (B-operand): Q[q=fr][hd contig 8], pre-scaled by 1/8
    short8 qh[2], ql[2];
#pragma unroll
    for (int kc = 0; kc < 2; kc++) {
        const size_t off = qkBase + (size_t)qrow * HD + kc * 32 + fg * 8;
        qh[kc] = ld8(Qhi + off);
        ql[kc] = ld8(Qlo + off);
    }

    f32x4 acco[4];                               // O^T: row d=df*16+fg*4+r, col q=fr
#pragma unroll
    for (int df = 0; df < 4; df++) acco[df] = f32x4{0.f, 0.f, 0.f, 0.f};
    float mrun = -__builtin_inff(), lrun = 0.f;  // per-lane scalars (own q-row)

    const size_t mrowBase = (size_t)qrow * S_LEN;

#pragma unroll 1
    for (int k0 = 0; k0 < S_LEN; k0 += 64) {
        __syncthreads();  // all waves done reading previous tile's LDS
#pragma unroll
        for (int i = 0; i < 2; i++) {
            const size_t ko = kSrc[i] + (size_t)k0 * HD;
            const size_t vo = vSrc[i] + k0;
            const size_t dst = (size_t)(i * 256 + w * 64) * 8;
            __builtin_amdgcn_global_load_lds((const AS1 void*)(Khi + ko), (AS3 void*)(asKH + dst), 16, 0, 0);
            __builtin_amdgcn_global_load_lds((const AS1 void*)(Klo + ko), (AS3 void*)(asKL + dst), 16, 0, 0);
            __builtin_amdgcn_global_load_lds((const AS1 void*)(Vhi + vo), (AS3 void*)(asVH + dst), 16, 0, 0);
            __builtin_amdgcn_global_load_lds((const AS1 void*)(Vlo + vo), (AS3 void*)(asVL + dst), 16, 0, 0);
        }
        // mask halves for this lane's q-row: k = k0 + h*32 + fg*8 + (0..7)
        const short8 mv0 = ld8(Mb + mrowBase + k0 + fg * 8);
        const short8 mv1 = ld8(Mb + mrowBase + k0 + 32 + fg * 8);
        __syncthreads();  // staging + mask loads complete (vmcnt drained)

        // ---- scores (swapped): sacc[cf][r] = S[q=fr][k0 + kmap(cf, fg*4..)]
        f32x4 sacc[4];
#pragma unroll
        for (int cf = 0; cf < 4; cf++) sacc[cf] = f32x4{0.f, 0.f, 0.f, 0.f};
#pragma unroll
        for (int cf = 0; cf < 4; cf++) {
#pragma unroll
            for (int kc = 0; kc < 2; kc++) {
                const int fi = cf * 2 + kc;
                const short8 kh = ld8(&KsH[(fi * 64 + lane) * 8]);
                const short8 kl = ld8(&KsL[(fi * 64 + lane) * 8]);
                sacc[cf] = mfma_bf16(kh, qh[kc], sacc[cf]);
                sacc[cf] = mfma_bf16(kl, qh[kc], sacc[cf]);
                sacc[cf] = mfma_bf16(kh, ql[kc], sacc[cf]);
            }
        }

        // ---- online softmax, all 16 q-rows of the wave at once
        float mx = sacc[0][0];
#pragma unroll
        for (int cf = 0; cf < 4; cf++)
#pragma unroll
            for (int r = 0; r < 4; r++) mx = fmaxf(mx, sacc[cf][r]);
        mx = fmaxf(mx, __shfl_xor(mx, 16, 64));
        mx = fmaxf(mx, __shfl_xor(mx, 32, 64));
        const float mnew = fmaxf(mrun, mx);
        const float alpha = __expf(mrun - mnew);
        mrun = mnew;

        float p[4][4], psum = 0.f;
#pragma unroll
        for (int cf = 0; cf < 4; cf++)
#pragma unroll
            for (int r = 0; r < 4; r++) {
                p[cf][r] = __expf(sacc[cf][r] - mnew);
                psum += p[cf][r];
            }
        psum += __shfl_xor(psum, 16, 64);
        psum += __shfl_xor(psum, 32, 64);
        lrun = lrun * alpha + psum;
#pragma unroll
        for (int df = 0; df < 4; df++) acco[df] *= alpha;

        // ---- masked P -> hi/lo PV B-fragments, pure in-register
        short8 phi[2], plo[2];
#pragma unroll
        for (int kc2 = 0; kc2 < 2; kc2++) {
#pragma unroll
            for (int j = 0; j < 8; j++) {
                const int cf = kc2 * 2 + (j >> 2), r = j & 3;
                const float mvf = (float)__builtin_bit_cast(
                    bf16_t, (ushort)((cf >> 1) ? mv1[(cf & 1) * 4 + r] : mv0[(cf & 1) * 4 + r]));
                const float pm = p[cf][r] * mvf;
                const bf16_t h = (bf16_t)pm;
                const bf16_t l = (bf16_t)(pm - (float)h);
                phi[kc2][j] = __builtin_bit_cast(short, h);
                plo[kc2][j] = __builtin_bit_cast(short, l);
            }
        }

        // ---- PV (swapped): acco[df] += VT-frag x P-frag
#pragma unroll
        for (int kc2 = 0; kc2 < 2; kc2++) {
#pragma unroll
            for (int df = 0; df < 4; df++) {
                const int fi = df * 2 + kc2;
                const short8 vh = ld8(&VsH[(fi * 64 + lane) * 8]);
                const short8 vl = ld8(&VsL[(fi * 64 + lane) * 8]);
                acco[df] = mfma_bf16(vh, phi[kc2], acco[df]);
                acco[df] = mfma_bf16(vl, phi[kc2], acco[df]);
                acco[df] = mfma_bf16(vh, plo[kc2], acco[df]);
            }
        }
    }

    // ---- epilogue: normalize (per-lane), split hi/lo, store O as [B,S,D]
    const int b = bh >> 4, hh = bh & (NH - 1);
    const float inv = 1.0f / lrun;
    const size_t obase = ((size_t)b * S_LEN + qrow) * DMODEL + hh * HD;
#pragma unroll
    for (int df = 0; df < 4; df++) {
#pragma unroll
        for (int r = 0; r < 4; r++) {
            const int d = df * 16 + fg * 4 + r;
            const float o = acco[df][r] * inv;
            const bf16_t h = (bf16_t)o;
            Ohi[obase + d] = h;
            Olo[obase + d] = (bf16_t)(o - (float)h);
        }
    }
}

// ---------------------------------------------------------------------------
extern "C" void kernel_launch(void* const* d_in, const int* in_sizes, int n_in,
                              void* d_out, int out_size, void* d_ws, size_t ws_size,
                              hipStream_t stream) {
    (void)in_sizes; (void)n_in; (void)out_size;
    if (ws_size < WS_REQUIRED) return;  // clean incorrect-output signal, not an OOB crash

    const float* q    = (const float*)d_in[0];
    const float* k    = (const float*)d_in[1];
    const float* v    = (const float*)d_in[2];
    const int*   mask = (const int*)  d_in[3];
    const float* wq   = (const float*)d_in[4];
    const float* wk   = (const float*)d_in[5];
    const float* wv   = (const float*)d_in[6];
    const float* wout = (const float*)d_in[7];
    char* ws = (char*)d_ws;
    float* out = (float*)d_out;

    const size_t nX = (size_t)BATCH * S_LEN * DMODEL;  // 4,194,304
    const size_t nW = (size_t)DMODEL * DMODEL;         // 1,048,576
    const size_t nM = (size_t)S_LEN * S_LEN;           // 4,194,304
    const dim3 blk(256);

    // fp32 -> hi/lo splits
    cvt_split_kernel<<<dim3(nX / 1024), blk, 0, stream>>>(q, (bf16_t*)(ws + OFF_XHI(0)), (bf16_t*)(ws + OFF_XLO(0)), (int)nX);
    cvt_split_kernel<<<dim3(nX / 1024), blk, 0, stream>>>(k, (bf16_t*)(ws + OFF_XHI(1)), (bf16_t*)(ws + OFF_XLO(1)), (int)nX);
    cvt_split_kernel<<<dim3(nX / 1024), blk, 0, stream>>>(v, (bf16_t*)(ws + OFF_XHI(2)), (bf16_t*)(ws + OFF_XLO(2)), (int)nX);
    cvt_split_kernel<<<dim3(nW / 1024), blk, 0, stream>>>(wq,   (bf16_t*)(ws + OFF_WHI(0)), (bf16_t*)(ws + OFF_WLO(0)), (int)nW);
    cvt_split_kernel<<<dim3(nW / 1024), blk, 0, stream>>>(wk,   (bf16_t*)(ws + OFF_WHI(1)), (bf16_t*)(ws + OFF_WLO(1)), (int)nW);
    cvt_split_kernel<<<dim3(nW / 1024), blk, 0, stream>>>(wv,   (bf16_t*)(ws + OFF_WHI(2)), (bf16_t*)(ws + OFF_WLO(2)), (int)nW);
    cvt_split_kernel<<<dim3(nW / 1024), blk, 0, stream>>>(wout, (bf16_t*)(ws + OFF_WHI(3)), (bf16_t*)(ws + OFF_WLO(3)), (int)nW);

    // q/k/v projections (z = 0/1/2), head-split epilogues
    gemm_split_kernel<0><<<dim3(32, 8, 3), blk, 0, stream>>>(ws, nullptr);

    // mask -> bf16 {0,1} into region freed by the input splits (stream-ordered
    // after the projections, which are the last readers of that region)
    cvt_mask_kernel<<<dim3(nM / 1024), blk, 0, stream>>>(mask, (bf16_t*)(ws + OFF_MASKB), (int)nM);

    // flash attention, swapped-operand, LDS-staged (1024 blocks)
    attn_kernel<<<dim3(S_LEN / 64, BATCH * NH), blk, 0, stream>>>(ws);

    // output projection -> d_out (fp32)
    gemm_split_kernel<1><<<dim3(32, 8, 1), blk, 0, stream>>>(ws, out);
}

// Round 8
// 441.721 us; speedup vs baseline: 1.7683x; 1.0993x over previous
//
#include <hip/hip_runtime.h>
#include <stdint.h>

// ---------------------------------------------------------------------------
// MHA forward, MI355X/gfx950.
// Reference: proj(q,k,v) -> scores=QK^T/8 -> softmax (FULL row) -> mask-fill
// (post-softmax, -1e-9 where mask==0) -> PV -> out @ wout^T.   All fp32.
//
// Split-bf16 (hi/lo) MFMA everywhere: a*b ~= ahi*bhi + ahi*blo + alo*bhi.
// The -1e-9 masked-fill value is approximated by 0 (contribution ~3e-8 abs).
//
// R8 (attn was 200us, MfmaUtil 22%, serial stage->sync->compute per tile;
//     GEMMs ~205us with 192 barriers / 16-MFMA phases):
//  1. attn: DOUBLE-BUFFERED staging.  Per tile: issue stage(t+1)+mask(t+1)
//     FIRST, then compute tile t from buf[cur]; one __syncthreads per tile
//     (its vmcnt(0) drain lands after compute covers the load latency).
//     setprio(1) around MFMA clusters.
//  2. GEMM: loop inverted -- stage Ahi/Alo/Bhi/Blo per K-step (32KB LDS),
//     all 3 split-products inside: 48 MFMA per barrier-pair (was 16),
//     barriers 192->64, gload_lds 384->256.
// ---------------------------------------------------------------------------

#define BATCH  2
#define S_LEN  2048
#define DMODEL 1024
#define NH     16
#define HD     64

typedef __bf16 bf16_t;
typedef short  short8 __attribute__((ext_vector_type(8)));   // 8 x bf16 bits
typedef float  f32x4  __attribute__((ext_vector_type(4)));

#define AS1 __attribute__((address_space(1)))
#define AS3 __attribute__((address_space(3)))

static constexpr size_t MB = (size_t)1 << 20;
static constexpr size_t WS_REQUIRED = 112 * MB;
// Workspace layout (byte offsets). High-water: 112 MB.
//  0..48MB   : input splits qx/kx/vx (hi,lo)   [dead after projections]
//  0..16MB   : (reused) attention output O hi/lo  [written by attn]
//  16..24MB  : (reused) mask as bf16 {0,1}        [written after projections]
//  48..64MB  : weight splits wq,wk,wv,wout (hi,lo)
//  64..112MB : Q (pre-scaled 1/8), K as [B,H,S,hd]; V transposed [B,H,hd,S]
#define OFF_XHI(z)  ((size_t)(z) * 16 * MB)
#define OFF_XLO(z)  (OFF_XHI(z) + 8 * MB)
#define OFF_WHI(z)  (48 * MB + (size_t)(z) * 4 * MB)
#define OFF_WLO(z)  (OFF_WHI(z) + 2 * MB)
#define OFF_PHI(z)  (64 * MB + (size_t)(z) * 16 * MB)   // z=0:Q 1:K 2:VT
#define OFF_PLO(z)  (OFF_PHI(z) + 8 * MB)
#define OFF_OHI     ((size_t)0)
#define OFF_OLO     (8 * MB)
#define OFF_MASKB   (16 * MB)

__device__ __forceinline__ f32x4 mfma_bf16(short8 a, short8 b, f32x4 c) {
    return __builtin_amdgcn_mfma_f32_16x16x32_bf16(a, b, c, 0, 0, 0);
}

__device__ __forceinline__ short8 ld8(const bf16_t* p) {
    return *reinterpret_cast<const short8*>(p);
}

// ---------------------------------------------------------------------------
// fp32 -> (bf16 hi, bf16 lo) split conversion, vectorized float4.
// ---------------------------------------------------------------------------
__global__ void cvt_split_kernel(const float* __restrict__ x,
                                 bf16_t* __restrict__ hi, bf16_t* __restrict__ lo,
                                 int n) {
    int i = (blockIdx.x * blockDim.x + threadIdx.x) * 4;
    if (i >= n) return;
    const float4 v = *reinterpret_cast<const float4*>(x + i);
    float s[4] = {v.x, v.y, v.z, v.w};
    ushort hbits[4], lbits[4];
#pragma unroll
    for (int j = 0; j < 4; j++) {
        bf16_t hh = (bf16_t)s[j];
        bf16_t ll = (bf16_t)(s[j] - (float)hh);
        hbits[j] = __builtin_bit_cast(ushort, hh);
        lbits[j] = __builtin_bit_cast(ushort, ll);
    }
    *reinterpret_cast<ushort4*>(hi + i) = ushort4{hbits[0], hbits[1], hbits[2], hbits[3]};
    *reinterpret_cast<ushort4*>(lo + i) = ushort4{lbits[0], lbits[1], lbits[2], lbits[3]};
}

// mask int32 -> bf16 {0,1}
__global__ void cvt_mask_kernel(const int* __restrict__ m, bf16_t* __restrict__ mb, int n) {
    int i = (blockIdx.x * blockDim.x + threadIdx.x) * 4;
    if (i >= n) return;
    const int4 v = *reinterpret_cast<const int4*>(m + i);
    int s[4] = {v.x, v.y, v.z, v.w};
    ushort b[4];
#pragma unroll
    for (int j = 0; j < 4; j++) {
        bf16_t t = (bf16_t)(s[j] ? 1.0f : 0.0f);
        b[j] = __builtin_bit_cast(ushort, t);
    }
    *reinterpret_cast<ushort4*>(mb + i) = ushort4{b[0], b[1], b[2], b[3]};
}

// ---------------------------------------------------------------------------
// Split-bf16 GEMM, C = A @ B^T (both operands K-contiguous).  128x128 tile,
// BK=32, 256 threads = 4 waves (2x2), each wave 64x64 = 4x4 16x16x32 frags.
// Per K-step: stage Ahi/Alo/Bhi/Blo (4 x 8KB), then 48 MFMA (3 split terms
// x 16 frag-pairs).  FINAL=0: grid.z picks q/k/v; epilogue head-splits
// (Q scaled 1/8; V transposed).  FINAL=1: output projection -> d_out fp32.
// ---------------------------------------------------------------------------
template <int FINAL>
__global__ __launch_bounds__(256, 2) void gemm_split_kernel(char* __restrict__ ws,
                                                            float* __restrict__ fout) {
    __shared__ __align__(16) bf16_t AsH[128 * 32];
    __shared__ __align__(16) bf16_t AsL[128 * 32];
    __shared__ __align__(16) bf16_t BsH[128 * 32];
    __shared__ __align__(16) bf16_t BsL[128 * 32];

    const int z = FINAL ? 3 : blockIdx.z;
    const bf16_t* Ahi = FINAL ? (const bf16_t*)(ws + OFF_OHI) : (const bf16_t*)(ws + OFF_XHI(z));
    const bf16_t* Alo = FINAL ? (const bf16_t*)(ws + OFF_OLO) : (const bf16_t*)(ws + OFF_XLO(z));
    const bf16_t* Bhi = (const bf16_t*)(ws + OFF_WHI(z));
    const bf16_t* Blo = (const bf16_t*)(ws + OFF_WLO(z));
    bf16_t* Ohi = FINAL ? nullptr : (bf16_t*)(ws + OFF_PHI(z));
    bf16_t* Olo = FINAL ? nullptr : (bf16_t*)(ws + OFF_PLO(z));
    const float scale = (!FINAL && z == 0) ? 0.125f : 1.0f;  // 1/sqrt(hd) folded into Q

    const int tid = threadIdx.x;
    const int lane = tid & 63, w = tid >> 6;
    const int wr = w >> 1, wc = w & 1;
    const int fr = lane & 15, fg = lane >> 4;
    const int m0 = blockIdx.x * 128, n0 = blockIdx.y * 128;
    const int K = 1024;

    f32x4 acc[4][4];
#pragma unroll
    for (int i = 0; i < 4; i++)
#pragma unroll
        for (int j = 0; j < 4; j++) acc[i][j] = f32x4{0.f, 0.f, 0.f, 0.f};

    AS3 bf16_t* asAH = (AS3 bf16_t*)AsH;
    AS3 bf16_t* asAL = (AS3 bf16_t*)AsL;
    AS3 bf16_t* asBH = (AS3 bf16_t*)BsH;
    AS3 bf16_t* asBL = (AS3 bf16_t*)BsL;

#pragma unroll 1
    for (int ks = 0; ks < K; ks += 32) {
        __syncthreads();  // previous compute done before restaging
#pragma unroll
        for (int i = 0; i < 2; i++) {
            // chunk c covers 16B: LDS byte c*16; global row c/4, 16B col (c&3)*16
            const int c = i * 256 + tid;
            const int row = c >> 2;
            const int ce = (c & 3) * 8;  // element offset within row
            const size_t gA = (size_t)(m0 + row) * K + ks + ce;
            const size_t gB = (size_t)(n0 + row) * K + ks + ce;
            const size_t d = (size_t)(i * 256 + w * 64) * 8;
            __builtin_amdgcn_global_load_lds((const AS1 void*)(Ahi + gA), (AS3 void*)(asAH + d), 16, 0, 0);
            __builtin_amdgcn_global_load_lds((const AS1 void*)(Alo + gA), (AS3 void*)(asAL + d), 16, 0, 0);
            __builtin_amdgcn_global_load_lds((const AS1 void*)(Bhi + gB), (AS3 void*)(asBH + d), 16, 0, 0);
            __builtin_amdgcn_global_load_lds((const AS1 void*)(Blo + gB), (AS3 void*)(asBL + d), 16, 0, 0);
        }
        __syncthreads();  // staging visible (syncthreads drains vmcnt)

        short8 afh[4], afl[4], bfh[4], bfl[4];
#pragma unroll
        for (int i = 0; i < 4; i++) {
            const int ao = (wr * 64 + i * 16 + fr) * 32 + fg * 8;
            const int bo = (wc * 64 + i * 16 + fr) * 32 + fg * 8;
            afh[i] = ld8(&AsH[ao]);
            afl[i] = ld8(&AsL[ao]);
            bfh[i] = ld8(&BsH[bo]);
            bfl[i] = ld8(&BsL[bo]);
        }
#pragma unroll
        for (int i = 0; i < 4; i++)
#pragma unroll
            for (int j = 0; j < 4; j++) {
                acc[i][j] = mfma_bf16(afh[i], bfh[j], acc[i][j]);
                acc[i][j] = mfma_bf16(afh[i], bfl[j], acc[i][j]);
                acc[i][j] = mfma_bf16(afl[i], bfh[j], acc[i][j]);
            }
    }

    // Epilogue. C/D frag: col = lane&15, row = (lane>>4)*4 + reg  [HW-verified]
#pragma unroll
    for (int i = 0; i < 4; i++) {
#pragma unroll
        for (int j = 0; j < 4; j++) {
            const int ncol = n0 + wc * 64 + j * 16 + fr;
#pragma unroll
            for (int r = 0; r < 4; r++) {
                const int m = m0 + wr * 64 + i * 16 + fg * 4 + r;
                const float val = acc[i][j][r] * scale;
                if (FINAL) {
                    fout[(size_t)m * DMODEL + ncol] = val;
                } else {
                    const bf16_t h = (bf16_t)val;
                    const bf16_t l = (bf16_t)(val - (float)h);
                    const int b = m >> 11, s = m & (S_LEN - 1);
                    const int hh = ncol >> 6, d = ncol & (HD - 1);
                    size_t idx;
                    if (z == 2) idx = ((size_t)(b * NH + hh) * HD + d) * S_LEN + s;      // VT [B,H,hd,S]
                    else        idx = ((size_t)(b * NH + hh) * S_LEN + s) * HD + d;      // [B,H,S,hd]
                    Ohi[idx] = h;
                    Olo[idx] = l;
                }
            }
        }
    }
}

// ---------------------------------------------------------------------------
// Flash attention, swapped-operand, DOUBLE-BUFFERED LDS staging.
// Grid: (S/64, B*H), 256 thr = 4 waves x 16 q-rows; lane (fr,fg) owns q-row
// w*16+fr.  Per tile: issue stage(t+1)+mask(t+1) FIRST, compute tile t from
// buf[cur], then one __syncthreads (vmcnt(0) drain lands after compute).
//
// K/V staged fragment-ordered (slot (frag,lane) = the 16B lane reads), kmap
// permutation baked into the staging SOURCE address.  QK^T swapped:
// mfma(K,Q) -> D[col=fr=q][row=k']; lane's 16 P values are exactly the two
// PV B-fragments; PV swapped: mfma(V^T,P).  Softmax in-lane + 2 shfls.
// ---------------------------------------------------------------------------
__global__ __launch_bounds__(256, 2) void attn_kernel(char* __restrict__ ws) {
    // [buf][frag 0..7][lane 0..63][8 bf16] = 2 x 8KB each, 64KB total
    __shared__ __align__(16) bf16_t KsH[2][8 * 64 * 8];
    __shared__ __align__(16) bf16_t KsL[2][8 * 64 * 8];
    __shared__ __align__(16) bf16_t VsH[2][8 * 64 * 8];
    __shared__ __align__(16) bf16_t VsL[2][8 * 64 * 8];

    const bf16_t* Qhi = (const bf16_t*)(ws + OFF_PHI(0));
    const bf16_t* Qlo = (const bf16_t*)(ws + OFF_PLO(0));
    const bf16_t* Khi = (const bf16_t*)(ws + OFF_PHI(1));
    const bf16_t* Klo = (const bf16_t*)(ws + OFF_PLO(1));
    const bf16_t* Vhi = (const bf16_t*)(ws + OFF_PHI(2));
    const bf16_t* Vlo = (const bf16_t*)(ws + OFF_PLO(2));
    const bf16_t* Mb  = (const bf16_t*)(ws + OFF_MASKB);
    bf16_t* Ohi = (bf16_t*)(ws + OFF_OHI);
    bf16_t* Olo = (bf16_t*)(ws + OFF_OLO);

    const int tid = threadIdx.x, lane = tid & 63, w = tid >> 6;
    const int fr = lane & 15, fg = lane >> 4;
    const int bh = blockIdx.y;
    const int q0 = blockIdx.x * 64;
    const int qrow = q0 + w * 16 + fr;          // this lane's q-row
    const size_t qkBase = (size_t)bh * S_LEN * HD;
    const size_t vtBase = (size_t)bh * HD * S_LEN;

    // Staging source offsets (slot s = i*256+tid -> lane l=s&63, frag f=(s>>6)&7):
    // K: f=cf*2+kc, row kmap(cf,l&15)=(cf&1)*4+(l&3)+((l>>2)&3)*8+(cf>>1)*32,
    //    col kc*32+(l>>4)*8.   V: f=df*2+kc2, row df*16+(l&15), col kc2*32+(l>>4)*8.
    size_t kSrc[2], vSrc[2];
#pragma unroll
    for (int i = 0; i < 2; i++) {
        const int s = i * 256 + tid;
        const int l = s & 63, f = (s >> 6) & 7;
        const int sfr = l & 15, sfg = l >> 4;
        const int cf = f >> 1, kc = f & 1;
        const int r = (cf & 1) * 4 + (sfr & 3) + (sfr >> 2) * 8 + (cf >> 1) * 32;
        kSrc[i] = qkBase + (size_t)r * HD + kc * 32 + sfg * 8;          // + k0*HD
        vSrc[i] = vtBase + (size_t)((f >> 1) * 16 + sfr) * S_LEN + (f & 1) * 32 + sfg * 8;  // + k0
    }

    // Q fragments (B-operand): Q[q=fr][hd contig 8], pre-scaled by 1/8
    short8 qh[2], ql[2];
#pragma unroll
    for (int kc = 0; kc < 2; kc++) {
        const size_t off = qkBase + (size_t)qrow * HD + kc * 32 + fg * 8;
        qh[kc] = ld8(Qhi + off);
        ql[kc] = ld8(Qlo + off);
    }

    f32x4 acco[4];                               // O^T: row d=df*16+fg*4+r, col q=fr
#pragma unroll
    for (int df = 0; df < 4; df++) acco[df] = f32x4{0.f, 0.f, 0.f, 0.f};
    float mrun = -__builtin_inff(), lrun = 0.f;  // per-lane scalars (own q-row)

    const size_t mrowBase = (size_t)qrow * S_LEN;

#define STAGE(K0, BUF)                                                                             \
    {                                                                                              \
        _Pragma("unroll") for (int i = 0; i < 2; i++) {                                            \
            const size_t ko = kSrc[i] + (size_t)(K0) * HD;                                         \
            const size_t vo = vSrc[i] + (K0);                                                      \
            const size_t dst = (size_t)(i * 256 + w * 64) * 8;                                     \
            __builtin_amdgcn_global_load_lds((const AS1 void*)(Khi + ko),                          \
                                             (AS3 void*)((AS3 bf16_t*)KsH[BUF] + dst), 16, 0, 0);  \
            __builtin_amdgcn_global_load_lds((const AS1 void*)(Klo + ko),                          \
                                             (AS3 void*)((AS3 bf16_t*)KsL[BUF] + dst), 16, 0, 0);  \
            __builtin_amdgcn_global_load_lds((const AS1 void*)(Vhi + vo),                          \
                                             (AS3 void*)((AS3 bf16_t*)VsH[BUF] + dst), 16, 0, 0);  \
            __builtin_amdgcn_global_load_lds((const AS1 void*)(Vlo + vo),                          \
                                             (AS3 void*)((AS3 bf16_t*)VsL[BUF] + dst), 16, 0, 0);  \
        }                                                                                          \
    }

    // ---- prologue: stage tile 0 into buf 0, prefetch its mask
    STAGE(0, 0)
    short8 mv0Cur = ld8(Mb + mrowBase + fg * 8);
    short8 mv1Cur = ld8(Mb + mrowBase + 32 + fg * 8);
    short8 mv0Nxt = mv0Cur, mv1Nxt = mv1Cur;
    __syncthreads();  // tile-0 staging + mask complete

    int cur = 0;
#pragma unroll 1
    for (int k0 = 0; k0 < S_LEN; k0 += 64) {
        // ---- issue next tile's staging + mask prefetch (overlaps compute below)
        if (k0 + 64 < S_LEN) {
            STAGE(k0 + 64, cur ^ 1)
            mv0Nxt = ld8(Mb + mrowBase + (k0 + 64) + fg * 8);
            mv1Nxt = ld8(Mb + mrowBase + (k0 + 64) + 32 + fg * 8);
        }

        // ---- scores (swapped): sacc[cf][r] = S[q=fr][k0 + kmap(cf, fg*4+r)]
        f32x4 sacc[4];
#pragma unroll
        for (int cf = 0; cf < 4; cf++) sacc[cf] = f32x4{0.f, 0.f, 0.f, 0.f};
        __builtin_amdgcn_s_setprio(1);
#pragma unroll
        for (int cf = 0; cf < 4; cf++) {
#pragma unroll
            for (int kc = 0; kc < 2; kc++) {
                const int fi = cf * 2 + kc;
                const short8 kh = ld8(&KsH[cur][(fi * 64 + lane) * 8]);
                const short8 kl = ld8(&KsL[cur][(fi * 64 + lane) * 8]);
                sacc[cf] = mfma_bf16(kh, qh[kc], sacc[cf]);
                sacc[cf] = mfma_bf16(kl, qh[kc], sacc[cf]);
                sacc[cf] = mfma_bf16(kh, ql[kc], sacc[cf]);
            }
        }
        __builtin_amdgcn_s_setprio(0);

        // ---- online softmax, all 16 q-rows of the wave at once
        float mx = sacc[0][0];
#pragma unroll
        for (int cf = 0; cf < 4; cf++)
#pragma unroll
            for (int r = 0; r < 4; r++) mx = fmaxf(mx, sacc[cf][r]);
        mx = fmaxf(mx, __shfl_xor(mx, 16, 64));
        mx = fmaxf(mx, __shfl_xor(mx, 32, 64));
        const float mnew = fmaxf(mrun, mx);
        const float alpha = __expf(mrun - mnew);
        mrun = mnew;

        float p[4][4], psum = 0.f;
#pragma unroll
        for (int cf = 0; cf < 4; cf++)
#pragma unroll
            for (int r = 0; r < 4; r++) {
                p[cf][r] = __expf(sacc[cf][r] - mnew);
                psum += p[cf][r];
            }
        psum += __shfl_xor(psum, 16, 64);
        psum += __shfl_xor(psum, 32, 64);
        lrun = lrun * alpha + psum;
#pragma unroll
        for (int df = 0; df < 4; df++) acco[df] *= alpha;

        // ---- masked P -> hi/lo PV B-fragments, pure in-register
        short8 phi[2], plo[2];
#pragma unroll
        for (int kc2 = 0; kc2 < 2; kc2++) {
#pragma unroll
            for (int j = 0; j < 8; j++) {
                const int cf = kc2 * 2 + (j >> 2), r = j & 3;
                const float mvf = (float)__builtin_bit_cast(
                    bf16_t, (ushort)((cf >> 1) ? mv1Cur[(cf & 1) * 4 + r] : mv0Cur[(cf & 1) * 4 + r]));
                const float pm = p[cf][r] * mvf;
                const bf16_t h = (bf16_t)pm;
                const bf16_t l = (bf16_t)(pm - (float)h);
                phi[kc2][j] = __builtin_bit_cast(short, h);
                plo[kc2][j] = __builtin_bit_cast(short, l);
            }
        }

        // ---- PV (swapped): acco[df] += VT-frag x P-frag
        __builtin_amdgcn_s_setprio(1);
#pragma unroll
        for (int kc2 = 0; kc2 < 2; kc2++) {
#pragma unroll
            for (int df = 0; df < 4; df++) {
                const int fi = df * 2 + kc2;
                const short8 vh = ld8(&VsH[cur][(fi * 64 + lane) * 8]);
                const short8 vl = ld8(&VsL[cur][(fi * 64 + lane) * 8]);
                acco[df] = mfma_bf16(vh, phi[kc2], acco[df]);
                acco[df] = mfma_bf16(vl, phi[kc2], acco[df]);
                acco[df] = mfma_bf16(vh, plo[kc2], acco[df]);
            }
        }
        __builtin_amdgcn_s_setprio(0);

        __syncthreads();  // drains vmcnt: next tile's staging+mask complete;
                          // all waves done reading buf[cur] -> reusable
        mv0Cur = mv0Nxt;
        mv1Cur = mv1Nxt;
        cur ^= 1;
    }
#undef STAGE

    // ---- epilogue: normalize (per-lane), split hi/lo, store O as [B,S,D]
    const int b = bh >> 4, hh = bh & (NH - 1);
    const float inv = 1.0f / lrun;
    const size_t obase = ((size_t)b * S_LEN + qrow) * DMODEL + hh * HD;
#pragma unroll
    for (int df = 0; df < 4; df++) {
#pragma unroll
        for (int r = 0; r < 4; r++) {
            const int d = df * 16 + fg * 4 + r;
            const float o = acco[df][r] * inv;
            const bf16_t h = (bf16_t)o;
            Ohi[obase + d] = h;
            Olo[obase + d] = (bf16_t)(o - (float)h);
        }
    }
}

// ---------------------------------------------------------------------------
extern "C" void kernel_launch(void* const* d_in, const int* in_sizes, int n_in,
                              void* d_out, int out_size, void* d_ws, size_t ws_size,
                              hipStream_t stream) {
    (void)in_sizes; (void)n_in; (void)out_size;
    if (ws_size < WS_REQUIRED) return;  // clean incorrect-output signal, not an OOB crash

    const float* q    = (const float*)d_in[0];
    const float* k    = (const float*)d_in[1];
    const float* v    = (const float*)d_in[2];
    const int*   mask = (const int*)  d_in[3];
    const float* wq   = (const float*)d_in[4];
    const float* wk   = (const float*)d_in[5];
    const float* wv   = (const float*)d_in[6];
    const float* wout = (const float*)d_in[7];
    char* ws = (char*)d_ws;
    float* out = (float*)d_out;

    const size_t nX = (size_t)BATCH * S_LEN * DMODEL;  // 4,194,304
    const size_t nW = (size_t)DMODEL * DMODEL;         // 1,048,576
    const size_t nM = (size_t)S_LEN * S_LEN;           // 4,194,304
    const dim3 blk(256);

    // fp32 -> hi/lo splits
    cvt_split_kernel<<<dim3(nX / 1024), blk, 0, stream>>>(q, (bf16_t*)(ws + OFF_XHI(0)), (bf16_t*)(ws + OFF_XLO(0)), (int)nX);
    cvt_split_kernel<<<dim3(nX / 1024), blk, 0, stream>>>(k, (bf16_t*)(ws + OFF_XHI(1)), (bf16_t*)(ws + OFF_XLO(1)), (int)nX);
    cvt_split_kernel<<<dim3(nX / 1024), blk, 0, stream>>>(v, (bf16_t*)(ws + OFF_XHI(2)), (bf16_t*)(ws + OFF_XLO(2)), (int)nX);
    cvt_split_kernel<<<dim3(nW / 1024), blk, 0, stream>>>(wq,   (bf16_t*)(ws + OFF_WHI(0)), (bf16_t*)(ws + OFF_WLO(0)), (int)nW);
    cvt_split_kernel<<<dim3(nW / 1024), blk, 0, stream>>>(wk,   (bf16_t*)(ws + OFF_WHI(1)), (bf16_t*)(ws + OFF_WLO(1)), (int)nW);
    cvt_split_kernel<<<dim3(nW / 1024), blk, 0, stream>>>(wv,   (bf16_t*)(ws + OFF_WHI(2)), (bf16_t*)(ws + OFF_WLO(2)), (int)nW);
    cvt_split_kernel<<<dim3(nW / 1024), blk, 0, stream>>>(wout, (bf16_t*)(ws + OFF_WHI(3)), (bf16_t*)(ws + OFF_WLO(3)), (int)nW);

    // q/k/v projections (z = 0/1/2), head-split epilogues
    gemm_split_kernel<0><<<dim3(32, 8, 3), blk, 0, stream>>>(ws, nullptr);

    // mask -> bf16 {0,1} into region freed by the input splits (stream-ordered
    // after the projections, which are the last readers of that region)
    cvt_mask_kernel<<<dim3(nM / 1024), blk, 0, stream>>>(mask, (bf16_t*)(ws + OFF_MASKB), (int)nM);

    // flash attention, swapped-operand, double-buffered (1024 blocks)
    attn_kernel<<<dim3(S_LEN / 64, BATCH * NH), blk, 0, stream>>>(ws);

    // output projection -> d_out (fp32)
    gemm_split_kernel<1><<<dim3(32, 8, 1), blk, 0, stream>>>(ws, out);
}

// Round 9
// 438.051 us; speedup vs baseline: 1.7831x; 1.0084x over previous
//
#include <hip/hip_runtime.h>
#include <stdint.h>

// ---------------------------------------------------------------------------
// MHA forward, MI355X/gfx950.
// Reference: proj(q,k,v) -> scores=QK^T/8 -> softmax (FULL row) -> mask-fill
// (post-softmax, -1e-9 where mask==0) -> PV -> out @ wout^T.   All fp32.
//
// Split-bf16 (hi/lo) MFMA everywhere: a*b ~= ahi*bhi + ahi*blo + alo*bhi.
// The -1e-9 masked-fill value is approximated by 0 (contribution ~3e-8 abs).
//
// R9 (attn was 185us, MfmaUtil 24%, occupancy 22% -- 64KB LDS = 2 blocks/CU;
//     waves barrier-synced into the serial softmax together):
//  1. LDS 64->48KB: K stays double-buffered (prefetch), V single-buffered
//     (stage V(t) at tile start; barrier A vmcnt-drain lands after
//     QK^T+softmax covers the latency; barrier B after PV protects Vs).
//     -> 3 blocks/CU, +50% waves/SIMD.
//  2. Softmax in exp2 domain (log2e folded into Q projection scale) +
//     defer-max (skip alpha-rescale while __all(mx <= mrun+8); P <= 2^8,
//     hi/lo split keeps 16-bit precision).
// ---------------------------------------------------------------------------

#define BATCH  2
#define S_LEN  2048
#define DMODEL 1024
#define NH     16
#define HD     64

typedef __bf16 bf16_t;
typedef short  short8 __attribute__((ext_vector_type(8)));   // 8 x bf16 bits
typedef float  f32x4  __attribute__((ext_vector_type(4)));

#define AS1 __attribute__((address_space(1)))
#define AS3 __attribute__((address_space(3)))

static constexpr size_t MB = (size_t)1 << 20;
static constexpr size_t WS_REQUIRED = 112 * MB;
// Workspace layout (byte offsets). High-water: 112 MB.
//  0..48MB   : input splits qx/kx/vx (hi,lo)   [dead after projections]
//  0..16MB   : (reused) attention output O hi/lo  [written by attn]
//  16..24MB  : (reused) mask as bf16 {0,1}        [written after projections]
//  48..64MB  : weight splits wq,wk,wv,wout (hi,lo)
//  64..112MB : Q (pre-scaled log2e/8), K as [B,H,S,hd]; V^T [B,H,hd,S]
#define OFF_XHI(z)  ((size_t)(z) * 16 * MB)
#define OFF_XLO(z)  (OFF_XHI(z) + 8 * MB)
#define OFF_WHI(z)  (48 * MB + (size_t)(z) * 4 * MB)
#define OFF_WLO(z)  (OFF_WHI(z) + 2 * MB)
#define OFF_PHI(z)  (64 * MB + (size_t)(z) * 16 * MB)   // z=0:Q 1:K 2:VT
#define OFF_PLO(z)  (OFF_PHI(z) + 8 * MB)
#define OFF_OHI     ((size_t)0)
#define OFF_OLO     (8 * MB)
#define OFF_MASKB   (16 * MB)

__device__ __forceinline__ f32x4 mfma_bf16(short8 a, short8 b, f32x4 c) {
    return __builtin_amdgcn_mfma_f32_16x16x32_bf16(a, b, c, 0, 0, 0);
}

__device__ __forceinline__ short8 ld8(const bf16_t* p) {
    return *reinterpret_cast<const short8*>(p);
}

// ---------------------------------------------------------------------------
// fp32 -> (bf16 hi, bf16 lo) split conversion, vectorized float4.
// ---------------------------------------------------------------------------
__global__ void cvt_split_kernel(const float* __restrict__ x,
                                 bf16_t* __restrict__ hi, bf16_t* __restrict__ lo,
                                 int n) {
    int i = (blockIdx.x * blockDim.x + threadIdx.x) * 4;
    if (i >= n) return;
    const float4 v = *reinterpret_cast<const float4*>(x + i);
    float s[4] = {v.x, v.y, v.z, v.w};
    ushort hbits[4], lbits[4];
#pragma unroll
    for (int j = 0; j < 4; j++) {
        bf16_t hh = (bf16_t)s[j];
        bf16_t ll = (bf16_t)(s[j] - (float)hh);
        hbits[j] = __builtin_bit_cast(ushort, hh);
        lbits[j] = __builtin_bit_cast(ushort, ll);
    }
    *reinterpret_cast<ushort4*>(hi + i) = ushort4{hbits[0], hbits[1], hbits[2], hbits[3]};
    *reinterpret_cast<ushort4*>(lo + i) = ushort4{lbits[0], lbits[1], lbits[2], lbits[3]};
}

// mask int32 -> bf16 {0,1}
__global__ void cvt_mask_kernel(const int* __restrict__ m, bf16_t* __restrict__ mb, int n) {
    int i = (blockIdx.x * blockDim.x + threadIdx.x) * 4;
    if (i >= n) return;
    const int4 v = *reinterpret_cast<const int4*>(m + i);
    int s[4] = {v.x, v.y, v.z, v.w};
    ushort b[4];
#pragma unroll
    for (int j = 0; j < 4; j++) {
        bf16_t t = (bf16_t)(s[j] ? 1.0f : 0.0f);
        b[j] = __builtin_bit_cast(ushort, t);
    }
    *reinterpret_cast<ushort4*>(mb + i) = ushort4{b[0], b[1], b[2], b[3]};
}

// ---------------------------------------------------------------------------
// Split-bf16 GEMM, C = A @ B^T (both operands K-contiguous).  128x128 tile,
// BK=32, 256 threads = 4 waves (2x2), each wave 64x64 = 4x4 16x16x32 frags.
// Per K-step: stage Ahi/Alo/Bhi/Blo (4 x 8KB), then 48 MFMA.
// FINAL=0: grid.z picks q/k/v; epilogue head-splits (Q scaled log2e/8;
// V transposed).  FINAL=1: output projection -> d_out fp32.
// ---------------------------------------------------------------------------
template <int FINAL>
__global__ __launch_bounds__(256, 2) void gemm_split_kernel(char* __restrict__ ws,
                                                            float* __restrict__ fout) {
    __shared__ __align__(16) bf16_t AsH[128 * 32];
    __shared__ __align__(16) bf16_t AsL[128 * 32];
    __shared__ __align__(16) bf16_t BsH[128 * 32];
    __shared__ __align__(16) bf16_t BsL[128 * 32];

    const int z = FINAL ? 3 : blockIdx.z;
    const bf16_t* Ahi = FINAL ? (const bf16_t*)(ws + OFF_OHI) : (const bf16_t*)(ws + OFF_XHI(z));
    const bf16_t* Alo = FINAL ? (const bf16_t*)(ws + OFF_OLO) : (const bf16_t*)(ws + OFF_XLO(z));
    const bf16_t* Bhi = (const bf16_t*)(ws + OFF_WHI(z));
    const bf16_t* Blo = (const bf16_t*)(ws + OFF_WLO(z));
    bf16_t* Ohi = FINAL ? nullptr : (bf16_t*)(ws + OFF_PHI(z));
    bf16_t* Olo = FINAL ? nullptr : (bf16_t*)(ws + OFF_PLO(z));
    // z==0: fold 1/sqrt(hd) AND log2(e) into Q (softmax runs in exp2 domain)
    const float scale = (!FINAL && z == 0) ? 0.18033688011112042f : 1.0f;

    const int tid = threadIdx.x;
    const int lane = tid & 63, w = tid >> 6;
    const int wr = w >> 1, wc = w & 1;
    const int fr = lane & 15, fg = lane >> 4;
    const int m0 = blockIdx.x * 128, n0 = blockIdx.y * 128;
    const int K = 1024;

    f32x4 acc[4][4];
#pragma unroll
    for (int i = 0; i < 4; i++)
#pragma unroll
        for (int j = 0; j < 4; j++) acc[i][j] = f32x4{0.f, 0.f, 0.f, 0.f};

    AS3 bf16_t* asAH = (AS3 bf16_t*)AsH;
    AS3 bf16_t* asAL = (AS3 bf16_t*)AsL;
    AS3 bf16_t* asBH = (AS3 bf16_t*)BsH;
    AS3 bf16_t* asBL = (AS3 bf16_t*)BsL;

#pragma unroll 1
    for (int ks = 0; ks < K; ks += 32) {
        __syncthreads();  // previous compute done before restaging
#pragma unroll
        for (int i = 0; i < 2; i++) {
            const int c = i * 256 + tid;
            const int row = c >> 2;
            const int ce = (c & 3) * 8;
            const size_t gA = (size_t)(m0 + row) * K + ks + ce;
            const size_t gB = (size_t)(n0 + row) * K + ks + ce;
            const size_t d = (size_t)(i * 256 + w * 64) * 8;
            __builtin_amdgcn_global_load_lds((const AS1 void*)(Ahi + gA), (AS3 void*)(asAH + d), 16, 0, 0);
            __builtin_amdgcn_global_load_lds((const AS1 void*)(Alo + gA), (AS3 void*)(asAL + d), 16, 0, 0);
            __builtin_amdgcn_global_load_lds((const AS1 void*)(Bhi + gB), (AS3 void*)(asBH + d), 16, 0, 0);
            __builtin_amdgcn_global_load_lds((const AS1 void*)(Blo + gB), (AS3 void*)(asBL + d), 16, 0, 0);
        }
        __syncthreads();  // staging visible (syncthreads drains vmcnt)

        short8 afh[4], afl[4], bfh[4], bfl[4];
#pragma unroll
        for (int i = 0; i < 4; i++) {
            const int ao = (wr * 64 + i * 16 + fr) * 32 + fg * 8;
            const int bo = (wc * 64 + i * 16 + fr) * 32 + fg * 8;
            afh[i] = ld8(&AsH[ao]);
            afl[i] = ld8(&AsL[ao]);
            bfh[i] = ld8(&BsH[bo]);
            bfl[i] = ld8(&BsL[bo]);
        }
#pragma unroll
        for (int i = 0; i < 4; i++)
#pragma unroll
            for (int j = 0; j < 4; j++) {
                acc[i][j] = mfma_bf16(afh[i], bfh[j], acc[i][j]);
                acc[i][j] = mfma_bf16(afh[i], bfl[j], acc[i][j]);
                acc[i][j] = mfma_bf16(afl[i], bfh[j], acc[i][j]);
            }
    }

    // Epilogue. C/D frag: col = lane&15, row = (lane>>4)*4 + reg  [HW-verified]
#pragma unroll
    for (int i = 0; i < 4; i++) {
#pragma unroll
        for (int j = 0; j < 4; j++) {
            const int ncol = n0 + wc * 64 + j * 16 + fr;
#pragma unroll
            for (int r = 0; r < 4; r++) {
                const int m = m0 + wr * 64 + i * 16 + fg * 4 + r;
                const float val = acc[i][j][r] * scale;
                if (FINAL) {
                    fout[(size_t)m * DMODEL + ncol] = val;
                } else {
                    const bf16_t h = (bf16_t)val;
                    const bf16_t l = (bf16_t)(val - (float)h);
                    const int b = m >> 11, s = m & (S_LEN - 1);
                    const int hh = ncol >> 6, d = ncol & (HD - 1);
                    size_t idx;
                    if (z == 2) idx = ((size_t)(b * NH + hh) * HD + d) * S_LEN + s;      // VT [B,H,hd,S]
                    else        idx = ((size_t)(b * NH + hh) * S_LEN + s) * HD + d;      // [B,H,S,hd]
                    Ohi[idx] = h;
                    Olo[idx] = l;
                }
            }
        }
    }
}

// ---------------------------------------------------------------------------
// Flash attention, swapped-operand.  K double-buffered, V single-buffered
// (48KB LDS -> 3 blocks/CU).  Grid: (S/64, B*H), 256 thr = 4 waves x 16
// q-rows; lane (fr,fg) owns q-row w*16+fr.
// Per tile t: STAGE_V(t) + STAGE_K(t+1,nxt) + mask(t+1) issued first;
// QK^T(t) from Ks[cur]; softmax; barrier A (vmcnt drain: V(t)/K(t+1) ready);
// PV(t) from Vs; barrier B (Vs reads done before next overwrite).
//
// K/V staged fragment-ordered (slot (frag,lane) = the 16B lane reads), kmap
// permutation baked into the staging SOURCE address.  QK^T swapped:
// mfma(K,Q); lane's 16 P values are exactly the two PV B-fragments; PV
// swapped: mfma(V^T,P).  Softmax exp2-domain, in-lane + 2 shfls, defer-max.
// ---------------------------------------------------------------------------
__global__ __launch_bounds__(256, 2) void attn_kernel(char* __restrict__ ws) {
    __shared__ __align__(16) bf16_t KsH[2][8 * 64 * 8];   // 2 x 8KB
    __shared__ __align__(16) bf16_t KsL[2][8 * 64 * 8];   // 2 x 8KB
    __shared__ __align__(16) bf16_t VsH[8 * 64 * 8];      // 8KB
    __shared__ __align__(16) bf16_t VsL[8 * 64 * 8];      // 8KB

    const bf16_t* Qhi = (const bf16_t*)(ws + OFF_PHI(0));
    const bf16_t* Qlo = (const bf16_t*)(ws + OFF_PLO(0));
    const bf16_t* Khi = (const bf16_t*)(ws + OFF_PHI(1));
    const bf16_t* Klo = (const bf16_t*)(ws + OFF_PLO(1));
    const bf16_t* Vhi = (const bf16_t*)(ws + OFF_PHI(2));
    const bf16_t* Vlo = (const bf16_t*)(ws + OFF_PLO(2));
    const bf16_t* Mb  = (const bf16_t*)(ws + OFF_MASKB);
    bf16_t* Ohi = (bf16_t*)(ws + OFF_OHI);
    bf16_t* Olo = (bf16_t*)(ws + OFF_OLO);

    const int tid = threadIdx.x, lane = tid & 63, w = tid >> 6;
    const int fr = lane & 15, fg = lane >> 4;
    const int bh = blockIdx.y;
    const int q0 = blockIdx.x * 64;
    const int qrow = q0 + w * 16 + fr;          // this lane's q-row
    const size_t qkBase = (size_t)bh * S_LEN * HD;
    const size_t vtBase = (size_t)bh * HD * S_LEN;

    // Staging source offsets (slot s = i*256+tid -> lane l=s&63, frag f=(s>>6)&7):
    // K: f=cf*2+kc, row kmap(cf,l&15)=(cf&1)*4+(l&3)+((l>>2)&3)*8+(cf>>1)*32,
    //    col kc*32+(l>>4)*8.   V: f=df*2+kc2, row df*16+(l&15), col kc2*32+(l>>4)*8.
    size_t kSrc[2], vSrc[2];
#pragma unroll
    for (int i = 0; i < 2; i++) {
        const int s = i * 256 + tid;
        const int l = s & 63, f = (s >> 6) & 7;
        const int sfr = l & 15, sfg = l >> 4;
        const int cf = f >> 1, kc = f & 1;
        const int r = (cf & 1) * 4 + (sfr & 3) + (sfr >> 2) * 8 + (cf >> 1) * 32;
        kSrc[i] = qkBase + (size_t)r * HD + kc * 32 + sfg * 8;          // + k0*HD
        vSrc[i] = vtBase + (size_t)((f >> 1) * 16 + sfr) * S_LEN + (f & 1) * 32 + sfg * 8;  // + k0
    }

    // Q fragments (B-operand): Q[q=fr][hd contig 8], pre-scaled by log2e/8
    short8 qh[2], ql[2];
#pragma unroll
    for (int kc = 0; kc < 2; kc++) {
        const size_t off = qkBase + (size_t)qrow * HD + kc * 32 + fg * 8;
        qh[kc] = ld8(Qhi + off);
        ql[kc] = ld8(Qlo + off);
    }

    f32x4 acco[4];                               // O^T: row d=df*16+fg*4+r, col q=fr
#pragma unroll
    for (int df = 0; df < 4; df++) acco[df] = f32x4{0.f, 0.f, 0.f, 0.f};
    float mrun = -__builtin_inff(), lrun = 0.f;  // per-lane scalars (own q-row)

    const size_t mrowBase = (size_t)qrow * S_LEN;

#define STAGE_K(K0, BUF)                                                                           \
    {                                                                                              \
        _Pragma("unroll") for (int i = 0; i < 2; i++) {                                            \
            const size_t ko = kSrc[i] + (size_t)(K0) * HD;                                         \
            const size_t dst = (size_t)(i * 256 + w * 64) * 8;                                     \
            __builtin_amdgcn_global_load_lds((const AS1 void*)(Khi + ko),                          \
                                             (AS3 void*)((AS3 bf16_t*)KsH[BUF] + dst), 16, 0, 0);  \
            __builtin_amdgcn_global_load_lds((const AS1 void*)(Klo + ko),                          \
                                             (AS3 void*)((AS3 bf16_t*)KsL[BUF] + dst), 16, 0, 0);  \
        }                                                                                          \
    }
#define STAGE_V(K0)                                                                                \
    {                                                                                              \
        _Pragma("unroll") for (int i = 0; i < 2; i++) {                                            \
            const size_t vo = vSrc[i] + (K0);                                                      \
            const size_t dst = (size_t)(i * 256 + w * 64) * 8;                                     \
            __builtin_amdgcn_global_load_lds((const AS1 void*)(Vhi + vo),                          \
                                             (AS3 void*)((AS3 bf16_t*)VsH + dst), 16, 0, 0);       \
            __builtin_amdgcn_global_load_lds((const AS1 void*)(Vlo + vo),                          \
                                             (AS3 void*)((AS3 bf16_t*)VsL + dst), 16, 0, 0);       \
        }                                                                                          \
    }

    // ---- prologue: stage K(0), prefetch mask(0)
    STAGE_K(0, 0)
    short8 mv0Cur = ld8(Mb + mrowBase + fg * 8);
    short8 mv1Cur = ld8(Mb + mrowBase + 32 + fg * 8);
    short8 mv0Nxt = mv0Cur, mv1Nxt = mv1Cur;
    __syncthreads();  // K(0) + mask(0) complete

    int cur = 0;
#pragma unroll 1
    for (int k0 = 0; k0 < S_LEN; k0 += 64) {
        // ---- issue V(t), K(t+1), mask(t+1) (overlap QK^T + softmax below)
        STAGE_V(k0)
        if (k0 + 64 < S_LEN) {
            STAGE_K(k0 + 64, cur ^ 1)
            mv0Nxt = ld8(Mb + mrowBase + (k0 + 64) + fg * 8);
            mv1Nxt = ld8(Mb + mrowBase + (k0 + 64) + 32 + fg * 8);
        }

        // ---- scores (swapped): sacc[cf][r] = S'[q=fr][k0 + kmap(cf, fg*4+r)]
        f32x4 sacc[4];
#pragma unroll
        for (int cf = 0; cf < 4; cf++) sacc[cf] = f32x4{0.f, 0.f, 0.f, 0.f};
        __builtin_amdgcn_s_setprio(1);
#pragma unroll
        for (int cf = 0; cf < 4; cf++) {
#pragma unroll
            for (int kc = 0; kc < 2; kc++) {
                const int fi = cf * 2 + kc;
                const short8 kh = ld8(&KsH[cur][(fi * 64 + lane) * 8]);
                const short8 kl = ld8(&KsL[cur][(fi * 64 + lane) * 8]);
                sacc[cf] = mfma_bf16(kh, qh[kc], sacc[cf]);
                sacc[cf] = mfma_bf16(kl, qh[kc], sacc[cf]);
                sacc[cf] = mfma_bf16(kh, ql[kc], sacc[cf]);
            }
        }
        __builtin_amdgcn_s_setprio(0);

        // ---- online softmax (exp2 domain), all 16 q-rows at once, defer-max
        float mx = sacc[0][0];
#pragma unroll
        for (int cf = 0; cf < 4; cf++)
#pragma unroll
            for (int r = 0; r < 4; r++) mx = fmaxf(mx, sacc[cf][r]);
        mx = fmaxf(mx, __shfl_xor(mx, 16, 64));
        mx = fmaxf(mx, __shfl_xor(mx, 32, 64));
        if (!__all(mx <= mrun + 8.0f)) {         // rescale only when needed
            const float mnew = fmaxf(mrun, mx);
            const float alpha = exp2f(mrun - mnew);
            mrun = mnew;
            lrun *= alpha;
#pragma unroll
            for (int df = 0; df < 4; df++) acco[df] *= alpha;
        }

        float p[4][4], psum = 0.f;
#pragma unroll
        for (int cf = 0; cf < 4; cf++)
#pragma unroll
            for (int r = 0; r < 4; r++) {
                p[cf][r] = exp2f(sacc[cf][r] - mrun);
                psum += p[cf][r];
            }
        psum += __shfl_xor(psum, 16, 64);
        psum += __shfl_xor(psum, 32, 64);
        lrun += psum;

        // ---- masked P -> hi/lo PV B-fragments, pure in-register
        short8 phi[2], plo[2];
#pragma unroll
        for (int kc2 = 0; kc2 < 2; kc2++) {
#pragma unroll
            for (int j = 0; j < 8; j++) {
                const int cf = kc2 * 2 + (j >> 2), r = j & 3;
                const float mvf = (float)__builtin_bit_cast(
                    bf16_t, (ushort)((cf >> 1) ? mv1Cur[(cf & 1) * 4 + r] : mv0Cur[(cf & 1) * 4 + r]));
                const float pm = p[cf][r] * mvf;
                const bf16_t h = (bf16_t)pm;
                const bf16_t l = (bf16_t)(pm - (float)h);
                phi[kc2][j] = __builtin_bit_cast(short, h);
                plo[kc2][j] = __builtin_bit_cast(short, l);
            }
        }

        __syncthreads();  // barrier A: drains vmcnt -> V(t), K(t+1), mask ready

        // ---- PV (swapped): acco[df] += VT-frag x P-frag
        __builtin_amdgcn_s_setprio(1);
#pragma unroll
        for (int kc2 = 0; kc2 < 2; kc2++) {
#pragma unroll
            for (int df = 0; df < 4; df++) {
                const int fi = df * 2 + kc2;
                const short8 vh = ld8(&VsH[(fi * 64 + lane) * 8]);
                const short8 vl = ld8(&VsL[(fi * 64 + lane) * 8]);
                acco[df] = mfma_bf16(vh, phi[kc2], acco[df]);
                acco[df] = mfma_bf16(vl, phi[kc2], acco[df]);
                acco[df] = mfma_bf16(vh, plo[kc2], acco[df]);
            }
        }
        __builtin_amdgcn_s_setprio(0);

        __syncthreads();  // barrier B: all waves done reading Vs before next STAGE_V
        mv0Cur = mv0Nxt;
        mv1Cur = mv1Nxt;
        cur ^= 1;
    }
#undef STAGE_K
#undef STAGE_V

    // ---- epilogue: normalize (per-lane), split hi/lo, store O as [B,S,D]
    const int b = bh >> 4, hh = bh & (NH - 1);
    const float inv = 1.0f / lrun;
    const size_t obase = ((size_t)b * S_LEN + qrow) * DMODEL + hh * HD;
#pragma unroll
    for (int df = 0; df < 4; df++) {
#pragma unroll
        for (int r = 0; r < 4; r++) {
            const int d = df * 16 + fg * 4 + r;
            const float o = acco[df][r] * inv;
            const bf16_t h = (bf16_t)o;
            Ohi[obase + d] = h;
            Olo[obase + d] = (bf16_t)(o - (float)h);
        }
    }
}

// ---------------------------------------------------------------------------
extern "C" void kernel_launch(void* const* d_in, const int* in_sizes, int n_in,
                              void* d_out, int out_size, void* d_ws, size_t ws_size,
                              hipStream_t stream) {
    (void)in_sizes; (void)n_in; (void)out_size;
    if (ws_size < WS_REQUIRED) return;  // clean incorrect-output signal, not an OOB crash

    const float* q    = (const float*)d_in[0];
    const float* k    = (const float*)d_in[1];
    const float* v    = (const float*)d_in[2];
    const int*   mask = (const int*)  d_in[3];
    const float* wq   = (const float*)d_in[4];
    const float* wk   = (const float*)d_in[5];
    const float* wv   = (const float*)d_in[6];
    const float* wout = (const float*)d_in[7];
    char* ws = (char*)d_ws;
    float* out = (float*)d_out;

    const size_t nX = (size_t)BATCH * S_LEN * DMODEL;  // 4,194,304
    const size_t nW = (size_t)DMODEL * DMODEL;         // 1,048,576
    const size_t nM = (size_t)S_LEN * S_LEN;           // 4,194,304
    const dim3 blk(256);

    // fp32 -> hi/lo splits
    cvt_split_kernel<<<dim3(nX / 1024), blk, 0, stream>>>(q, (bf16_t*)(ws + OFF_XHI(0)), (bf16_t*)(ws + OFF_XLO(0)), (int)nX);
    cvt_split_kernel<<<dim3(nX / 1024), blk, 0, stream>>>(k, (bf16_t*)(ws + OFF_XHI(1)), (bf16_t*)(ws + OFF_XLO(1)), (int)nX);
    cvt_split_kernel<<<dim3(nX / 1024), blk, 0, stream>>>(v, (bf16_t*)(ws + OFF_XHI(2)), (bf16_t*)(ws + OFF_XLO(2)), (int)nX);
    cvt_split_kernel<<<dim3(nW / 1024), blk, 0, stream>>>(wq,   (bf16_t*)(ws + OFF_WHI(0)), (bf16_t*)(ws + OFF_WLO(0)), (int)nW);
    cvt_split_kernel<<<dim3(nW / 1024), blk, 0, stream>>>(wk,   (bf16_t*)(ws + OFF_WHI(1)), (bf16_t*)(ws + OFF_WLO(1)), (int)nW);
    cvt_split_kernel<<<dim3(nW / 1024), blk, 0, stream>>>(wv,   (bf16_t*)(ws + OFF_WHI(2)), (bf16_t*)(ws + OFF_WLO(2)), (int)nW);
    cvt_split_kernel<<<dim3(nW / 1024), blk, 0, stream>>>(wout, (bf16_t*)(ws + OFF_WHI(3)), (bf16_t*)(ws + OFF_WLO(3)), (int)nW);

    // q/k/v projections (z = 0/1/2), head-split epilogues
    gemm_split_kernel<0><<<dim3(32, 8, 3), blk, 0, stream>>>(ws, nullptr);

    // mask -> bf16 {0,1} into region freed by the input splits
    cvt_mask_kernel<<<dim3(nM / 1024), blk, 0, stream>>>(mask, (bf16_t*)(ws + OFF_MASKB), (int)nM);

    // flash attention (1024 blocks, 3 blocks/CU)
    attn_kernel<<<dim3(S_LEN / 64, BATCH * NH), blk, 0, stream>>>(ws);

    // output projection -> d_out (fp32)
    gemm_split_kernel<1><<<dim3(32, 8, 1), blk, 0, stream>>>(ws, out);
}

// Round 10
// 419.306 us; speedup vs baseline: 1.8628x; 1.0447x over previous
//
#include <hip/hip_runtime.h>
#include <stdint.h>

// ---------------------------------------------------------------------------
// MHA forward, MI355X/gfx950.
// Reference: proj(q,k,v) -> scores=QK^T/8 -> softmax (FULL row) -> mask-fill
// (post-softmax, -1e-9 where mask==0) -> PV -> out @ wout^T.   All fp32.
//
// Split-bf16 (hi/lo) MFMA everywhere: a*b ~= ahi*bhi + ahi*blo + alo*bhi.
// The -1e-9 masked-fill value is approximated by 0 (contribution ~3e-8 abs).
//
// R10 (attn stuck ~190us; ds_read arithmetic: each wave reads the whole
//      32KB tile -> ~82us of LDS pipe at 12cy/ds_read_b128 = co-limiter):
//   attn mf=2: each wave owns 32 q-rows (2 fragments).  The SAME K/V
//   fragment registers feed both mf MFMAs -> LDS-read bytes per MFMA
//   halve (1 ds_read : 6 MFMA), staging + K/V HBM re-reads per bh halve.
//   Grid (S/128, B*H) = 512 blocks.  K dbuf + V single buf (48KB LDS).
// ---------------------------------------------------------------------------

#define BATCH  2
#define S_LEN  2048
#define DMODEL 1024
#define NH     16
#define HD     64

typedef __bf16 bf16_t;
typedef short  short8 __attribute__((ext_vector_type(8)));   // 8 x bf16 bits
typedef float  f32x4  __attribute__((ext_vector_type(4)));

#define AS1 __attribute__((address_space(1)))
#define AS3 __attribute__((address_space(3)))

static constexpr size_t MB = (size_t)1 << 20;
static constexpr size_t WS_REQUIRED = 112 * MB;
// Workspace layout (byte offsets). High-water: 112 MB.
//  0..48MB   : input splits qx/kx/vx (hi,lo)   [dead after projections]
//  0..16MB   : (reused) attention output O hi/lo  [written by attn]
//  16..24MB  : (reused) mask as bf16 {0,1}        [written after projections]
//  48..64MB  : weight splits wq,wk,wv,wout (hi,lo)
//  64..112MB : Q (pre-scaled log2e/8), K as [B,H,S,hd]; V^T [B,H,hd,S]
#define OFF_XHI(z)  ((size_t)(z) * 16 * MB)
#define OFF_XLO(z)  (OFF_XHI(z) + 8 * MB)
#define OFF_WHI(z)  (48 * MB + (size_t)(z) * 4 * MB)
#define OFF_WLO(z)  (OFF_WHI(z) + 2 * MB)
#define OFF_PHI(z)  (64 * MB + (size_t)(z) * 16 * MB)   // z=0:Q 1:K 2:VT
#define OFF_PLO(z)  (OFF_PHI(z) + 8 * MB)
#define OFF_OHI     ((size_t)0)
#define OFF_OLO     (8 * MB)
#define OFF_MASKB   (16 * MB)

__device__ __forceinline__ f32x4 mfma_bf16(short8 a, short8 b, f32x4 c) {
    return __builtin_amdgcn_mfma_f32_16x16x32_bf16(a, b, c, 0, 0, 0);
}

__device__ __forceinline__ short8 ld8(const bf16_t* p) {
    return *reinterpret_cast<const short8*>(p);
}

// ---------------------------------------------------------------------------
// fp32 -> (bf16 hi, bf16 lo) split conversion, vectorized float4.
// ---------------------------------------------------------------------------
__global__ void cvt_split_kernel(const float* __restrict__ x,
                                 bf16_t* __restrict__ hi, bf16_t* __restrict__ lo,
                                 int n) {
    int i = (blockIdx.x * blockDim.x + threadIdx.x) * 4;
    if (i >= n) return;
    const float4 v = *reinterpret_cast<const float4*>(x + i);
    float s[4] = {v.x, v.y, v.z, v.w};
    ushort hbits[4], lbits[4];
#pragma unroll
    for (int j = 0; j < 4; j++) {
        bf16_t hh = (bf16_t)s[j];
        bf16_t ll = (bf16_t)(s[j] - (float)hh);
        hbits[j] = __builtin_bit_cast(ushort, hh);
        lbits[j] = __builtin_bit_cast(ushort, ll);
    }
    *reinterpret_cast<ushort4*>(hi + i) = ushort4{hbits[0], hbits[1], hbits[2], hbits[3]};
    *reinterpret_cast<ushort4*>(lo + i) = ushort4{lbits[0], lbits[1], lbits[2], lbits[3]};
}

// mask int32 -> bf16 {0,1}
__global__ void cvt_mask_kernel(const int* __restrict__ m, bf16_t* __restrict__ mb, int n) {
    int i = (blockIdx.x * blockDim.x + threadIdx.x) * 4;
    if (i >= n) return;
    const int4 v = *reinterpret_cast<const int4*>(m + i);
    int s[4] = {v.x, v.y, v.z, v.w};
    ushort b[4];
#pragma unroll
    for (int j = 0; j < 4; j++) {
        bf16_t t = (bf16_t)(s[j] ? 1.0f : 0.0f);
        b[j] = __builtin_bit_cast(ushort, t);
    }
    *reinterpret_cast<ushort4*>(mb + i) = ushort4{b[0], b[1], b[2], b[3]};
}

// ---------------------------------------------------------------------------
// Split-bf16 GEMM, C = A @ B^T (both operands K-contiguous).  128x128 tile,
// BK=32, 256 threads = 4 waves (2x2), each wave 64x64 = 4x4 16x16x32 frags.
// Per K-step: stage Ahi/Alo/Bhi/Blo (4 x 8KB), then 48 MFMA.
// FINAL=0: grid.z picks q/k/v; epilogue head-splits (Q scaled log2e/8;
// V transposed).  FINAL=1: output projection -> d_out fp32.
// ---------------------------------------------------------------------------
template <int FINAL>
__global__ __launch_bounds__(256, 2) void gemm_split_kernel(char* __restrict__ ws,
                                                            float* __restrict__ fout) {
    __shared__ __align__(16) bf16_t AsH[128 * 32];
    __shared__ __align__(16) bf16_t AsL[128 * 32];
    __shared__ __align__(16) bf16_t BsH[128 * 32];
    __shared__ __align__(16) bf16_t BsL[128 * 32];

    const int z = FINAL ? 3 : blockIdx.z;
    const bf16_t* Ahi = FINAL ? (const bf16_t*)(ws + OFF_OHI) : (const bf16_t*)(ws + OFF_XHI(z));
    const bf16_t* Alo = FINAL ? (const bf16_t*)(ws + OFF_OLO) : (const bf16_t*)(ws + OFF_XLO(z));
    const bf16_t* Bhi = (const bf16_t*)(ws + OFF_WHI(z));
    const bf16_t* Blo = (const bf16_t*)(ws + OFF_WLO(z));
    bf16_t* Ohi = FINAL ? nullptr : (bf16_t*)(ws + OFF_PHI(z));
    bf16_t* Olo = FINAL ? nullptr : (bf16_t*)(ws + OFF_PLO(z));
    // z==0: fold 1/sqrt(hd) AND log2(e) into Q (softmax runs in exp2 domain)
    const float scale = (!FINAL && z == 0) ? 0.18033688011112042f : 1.0f;

    const int tid = threadIdx.x;
    const int lane = tid & 63, w = tid >> 6;
    const int wr = w >> 1, wc = w & 1;
    const int fr = lane & 15, fg = lane >> 4;
    const int m0 = blockIdx.x * 128, n0 = blockIdx.y * 128;
    const int K = 1024;

    f32x4 acc[4][4];
#pragma unroll
    for (int i = 0; i < 4; i++)
#pragma unroll
        for (int j = 0; j < 4; j++) acc[i][j] = f32x4{0.f, 0.f, 0.f, 0.f};

    AS3 bf16_t* asAH = (AS3 bf16_t*)AsH;
    AS3 bf16_t* asAL = (AS3 bf16_t*)AsL;
    AS3 bf16_t* asBH = (AS3 bf16_t*)BsH;
    AS3 bf16_t* asBL = (AS3 bf16_t*)BsL;

#pragma unroll 1
    for (int ks = 0; ks < K; ks += 32) {
        __syncthreads();  // previous compute done before restaging
#pragma unroll
        for (int i = 0; i < 2; i++) {
            const int c = i * 256 + tid;
            const int row = c >> 2;
            const int ce = (c & 3) * 8;
            const size_t gA = (size_t)(m0 + row) * K + ks + ce;
            const size_t gB = (size_t)(n0 + row) * K + ks + ce;
            const size_t d = (size_t)(i * 256 + w * 64) * 8;
            __builtin_amdgcn_global_load_lds((const AS1 void*)(Ahi + gA), (AS3 void*)(asAH + d), 16, 0, 0);
            __builtin_amdgcn_global_load_lds((const AS1 void*)(Alo + gA), (AS3 void*)(asAL + d), 16, 0, 0);
            __builtin_amdgcn_global_load_lds((const AS1 void*)(Bhi + gB), (AS3 void*)(asBH + d), 16, 0, 0);
            __builtin_amdgcn_global_load_lds((const AS1 void*)(Blo + gB), (AS3 void*)(asBL + d), 16, 0, 0);
        }
        __syncthreads();  // staging visible (syncthreads drains vmcnt)

        short8 afh[4], afl[4], bfh[4], bfl[4];
#pragma unroll
        for (int i = 0; i < 4; i++) {
            const int ao = (wr * 64 + i * 16 + fr) * 32 + fg * 8;
            const int bo = (wc * 64 + i * 16 + fr) * 32 + fg * 8;
            afh[i] = ld8(&AsH[ao]);
            afl[i] = ld8(&AsL[ao]);
            bfh[i] = ld8(&BsH[bo]);
            bfl[i] = ld8(&BsL[bo]);
        }
#pragma unroll
        for (int i = 0; i < 4; i++)
#pragma unroll
            for (int j = 0; j < 4; j++) {
                acc[i][j] = mfma_bf16(afh[i], bfh[j], acc[i][j]);
                acc[i][j] = mfma_bf16(afh[i], bfl[j], acc[i][j]);
                acc[i][j] = mfma_bf16(afl[i], bfh[j], acc[i][j]);
            }
    }

    // Epilogue. C/D frag: col = lane&15, row = (lane>>4)*4 + reg  [HW-verified]
#pragma unroll
    for (int i = 0; i < 4; i++) {
#pragma unroll
        for (int j = 0; j < 4; j++) {
            const int ncol = n0 + wc * 64 + j * 16 + fr;
#pragma unroll
            for (int r = 0; r < 4; r++) {
                const int m = m0 + wr * 64 + i * 16 + fg * 4 + r;
                const float val = acc[i][j][r] * scale;
                if (FINAL) {
                    fout[(size_t)m * DMODEL + ncol] = val;
                } else {
                    const bf16_t h = (bf16_t)val;
                    const bf16_t l = (bf16_t)(val - (float)h);
                    const int b = m >> 11, s = m & (S_LEN - 1);
                    const int hh = ncol >> 6, d = ncol & (HD - 1);
                    size_t idx;
                    if (z == 2) idx = ((size_t)(b * NH + hh) * HD + d) * S_LEN + s;      // VT [B,H,hd,S]
                    else        idx = ((size_t)(b * NH + hh) * S_LEN + s) * HD + d;      // [B,H,S,hd]
                    Ohi[idx] = h;
                    Olo[idx] = l;
                }
            }
        }
    }
}

// ---------------------------------------------------------------------------
// Flash attention, swapped-operand, mf=2 (32 q-rows/wave).  K dbuf + V
// single buf (48KB LDS).  Grid: (S/128, B*H), 256 thr = 4 waves; lane
// (fr,fg) owns q-rows q0 + w*32 + {0,16} + fr.
// Per tile t: STAGE_V(t) + STAGE_K(t+1) + mask(t+1) issued first; QK^T(t)
// from Ks[cur] (each K fragment read feeds BOTH mf fragments -> LDS reads
// per MFMA halved); softmax per mf; barrier A (vmcnt drain); PV from Vs
// (each V fragment feeds both mf); barrier B.
// Softmax exp2-domain, in-lane + 2 shfls per mf, defer-max (THR=8).
// ---------------------------------------------------------------------------
__global__ __launch_bounds__(256, 2) void attn_kernel(char* __restrict__ ws) {
    __shared__ __align__(16) bf16_t KsH[2][8 * 64 * 8];   // 2 x 8KB
    __shared__ __align__(16) bf16_t KsL[2][8 * 64 * 8];   // 2 x 8KB
    __shared__ __align__(16) bf16_t VsH[8 * 64 * 8];      // 8KB
    __shared__ __align__(16) bf16_t VsL[8 * 64 * 8];      // 8KB

    const bf16_t* Qhi = (const bf16_t*)(ws + OFF_PHI(0));
    const bf16_t* Qlo = (const bf16_t*)(ws + OFF_PLO(0));
    const bf16_t* Khi = (const bf16_t*)(ws + OFF_PHI(1));
    const bf16_t* Klo = (const bf16_t*)(ws + OFF_PLO(1));
    const bf16_t* Vhi = (const bf16_t*)(ws + OFF_PHI(2));
    const bf16_t* Vlo = (const bf16_t*)(ws + OFF_PLO(2));
    const bf16_t* Mb  = (const bf16_t*)(ws + OFF_MASKB);
    bf16_t* Ohi = (bf16_t*)(ws + OFF_OHI);
    bf16_t* Olo = (bf16_t*)(ws + OFF_OLO);

    const int tid = threadIdx.x, lane = tid & 63, w = tid >> 6;
    const int fr = lane & 15, fg = lane >> 4;
    const int bh = blockIdx.y;
    const int q0 = blockIdx.x * 128;
    const int qrow0 = q0 + w * 32 + fr;         // mf row = qrow0 + mf*16
    const size_t qkBase = (size_t)bh * S_LEN * HD;
    const size_t vtBase = (size_t)bh * HD * S_LEN;

    // Staging source offsets (slot s = i*256+tid -> lane l=s&63, frag f=(s>>6)&7):
    // K: f=cf*2+kc, row kmap(cf,l&15)=(cf&1)*4+(l&3)+((l>>2)&3)*8+(cf>>1)*32,
    //    col kc*32+(l>>4)*8.   V: f=df*2+kc2, row df*16+(l&15), col kc2*32+(l>>4)*8.
    size_t kSrc[2], vSrc[2];
#pragma unroll
    for (int i = 0; i < 2; i++) {
        const int s = i * 256 + tid;
        const int l = s & 63, f = (s >> 6) & 7;
        const int sfr = l & 15, sfg = l >> 4;
        const int cf = f >> 1, kc = f & 1;
        const int r = (cf & 1) * 4 + (sfr & 3) + (sfr >> 2) * 8 + (cf >> 1) * 32;
        kSrc[i] = qkBase + (size_t)r * HD + kc * 32 + sfg * 8;          // + k0*HD
        vSrc[i] = vtBase + (size_t)((f >> 1) * 16 + sfr) * S_LEN + (f & 1) * 32 + sfg * 8;  // + k0
    }

    // Q fragments (B-operand): Q[q][hd contig 8], pre-scaled by log2e/8
    short8 qh[2][2], ql[2][2];
#pragma unroll
    for (int mf = 0; mf < 2; mf++)
#pragma unroll
        for (int kc = 0; kc < 2; kc++) {
            const size_t off = qkBase + (size_t)(qrow0 + mf * 16) * HD + kc * 32 + fg * 8;
            qh[mf][kc] = ld8(Qhi + off);
            ql[mf][kc] = ld8(Qlo + off);
        }

    f32x4 acco[2][4];                            // O^T per mf
#pragma unroll
    for (int mf = 0; mf < 2; mf++)
#pragma unroll
        for (int df = 0; df < 4; df++) acco[mf][df] = f32x4{0.f, 0.f, 0.f, 0.f};
    float mrun[2] = {-__builtin_inff(), -__builtin_inff()};
    float lrun[2] = {0.f, 0.f};

    const size_t mrowBase0 = (size_t)qrow0 * S_LEN;
    const size_t mrowBase1 = (size_t)(qrow0 + 16) * S_LEN;

#define STAGE_K(K0, BUF)                                                                           \
    {                                                                                              \
        _Pragma("unroll") for (int i = 0; i < 2; i++) {                                            \
            const size_t ko = kSrc[i] + (size_t)(K0) * HD;                                         \
            const size_t dst = (size_t)(i * 256 + w * 64) * 8;                                     \
            __builtin_amdgcn_global_load_lds((const AS1 void*)(Khi + ko),                          \
                                             (AS3 void*)((AS3 bf16_t*)KsH[BUF] + dst), 16, 0, 0);  \
            __builtin_amdgcn_global_load_lds((const AS1 void*)(Klo + ko),                          \
                                             (AS3 void*)((AS3 bf16_t*)KsL[BUF] + dst), 16, 0, 0);  \
        }                                                                                          \
    }
#define STAGE_V(K0)                                                                                \
    {                                                                                              \
        _Pragma("unroll") for (int i = 0; i < 2; i++) {                                            \
            const size_t vo = vSrc[i] + (K0);                                                      \
            const size_t dst = (size_t)(i * 256 + w * 64) * 8;                                     \
            __builtin_amdgcn_global_load_lds((const AS1 void*)(Vhi + vo),                          \
                                             (AS3 void*)((AS3 bf16_t*)VsH + dst), 16, 0, 0);       \
            __builtin_amdgcn_global_load_lds((const AS1 void*)(Vlo + vo),                          \
                                             (AS3 void*)((AS3 bf16_t*)VsL + dst), 16, 0, 0);       \
        }                                                                                          \
    }

    // ---- prologue: stage K(0), prefetch mask(0) for both mf rows
    STAGE_K(0, 0)
    short8 mvCur[2][2], mvNxt[2][2];
    mvCur[0][0] = ld8(Mb + mrowBase0 + fg * 8);
    mvCur[0][1] = ld8(Mb + mrowBase0 + 32 + fg * 8);
    mvCur[1][0] = ld8(Mb + mrowBase1 + fg * 8);
    mvCur[1][1] = ld8(Mb + mrowBase1 + 32 + fg * 8);
#pragma unroll
    for (int mf = 0; mf < 2; mf++)
#pragma unroll
        for (int hh = 0; hh < 2; hh++) mvNxt[mf][hh] = mvCur[mf][hh];
    __syncthreads();  // K(0) + mask(0) complete

    int cur = 0;
#pragma unroll 1
    for (int k0 = 0; k0 < S_LEN; k0 += 64) {
        // ---- issue V(t), K(t+1), mask(t+1) (overlap QK^T + softmax below)
        STAGE_V(k0)
        if (k0 + 64 < S_LEN) {
            STAGE_K(k0 + 64, cur ^ 1)
            mvNxt[0][0] = ld8(Mb + mrowBase0 + (k0 + 64) + fg * 8);
            mvNxt[0][1] = ld8(Mb + mrowBase0 + (k0 + 64) + 32 + fg * 8);
            mvNxt[1][0] = ld8(Mb + mrowBase1 + (k0 + 64) + fg * 8);
            mvNxt[1][1] = ld8(Mb + mrowBase1 + (k0 + 64) + 32 + fg * 8);
        }

        // ---- scores (swapped): each K fragment feeds BOTH mf fragments
        f32x4 sacc[2][4];
#pragma unroll
        for (int mf = 0; mf < 2; mf++)
#pragma unroll
            for (int cf = 0; cf < 4; cf++) sacc[mf][cf] = f32x4{0.f, 0.f, 0.f, 0.f};
        __builtin_amdgcn_s_setprio(1);
#pragma unroll
        for (int cf = 0; cf < 4; cf++) {
#pragma unroll
            for (int kc = 0; kc < 2; kc++) {
                const int fi = cf * 2 + kc;
                const short8 kh = ld8(&KsH[cur][(fi * 64 + lane) * 8]);
                const short8 kl = ld8(&KsL[cur][(fi * 64 + lane) * 8]);
#pragma unroll
                for (int mf = 0; mf < 2; mf++) {
                    sacc[mf][cf] = mfma_bf16(kh, qh[mf][kc], sacc[mf][cf]);
                    sacc[mf][cf] = mfma_bf16(kl, qh[mf][kc], sacc[mf][cf]);
                    sacc[mf][cf] = mfma_bf16(kh, ql[mf][kc], sacc[mf][cf]);
                }
            }
        }
        __builtin_amdgcn_s_setprio(0);

        // ---- online softmax (exp2 domain) per mf, in-lane + 2 shfls, defer-max
        float p[2][4][4];
#pragma unroll
        for (int mf = 0; mf < 2; mf++) {
            float mx = sacc[mf][0][0];
#pragma unroll
            for (int cf = 0; cf < 4; cf++)
#pragma unroll
                for (int r = 0; r < 4; r++) mx = fmaxf(mx, sacc[mf][cf][r]);
            mx = fmaxf(mx, __shfl_xor(mx, 16, 64));
            mx = fmaxf(mx, __shfl_xor(mx, 32, 64));
            if (!__all(mx <= mrun[mf] + 8.0f)) {  // rescale only when needed
                const float mnew = fmaxf(mrun[mf], mx);
                const float alpha = exp2f(mrun[mf] - mnew);
                mrun[mf] = mnew;
                lrun[mf] *= alpha;
#pragma unroll
                for (int df = 0; df < 4; df++) acco[mf][df] *= alpha;
            }
            float psum = 0.f;
#pragma unroll
            for (int cf = 0; cf < 4; cf++)
#pragma unroll
                for (int r = 0; r < 4; r++) {
                    p[mf][cf][r] = exp2f(sacc[mf][cf][r] - mrun[mf]);
                    psum += p[mf][cf][r];
                }
            psum += __shfl_xor(psum, 16, 64);
            psum += __shfl_xor(psum, 32, 64);
            lrun[mf] += psum;
        }

        // ---- masked P -> hi/lo PV B-fragments, pure in-register
        short8 phi[2][2], plo[2][2];
#pragma unroll
        for (int mf = 0; mf < 2; mf++)
#pragma unroll
            for (int kc2 = 0; kc2 < 2; kc2++)
#pragma unroll
                for (int j = 0; j < 8; j++) {
                    const int cf = kc2 * 2 + (j >> 2), r = j & 3;
                    const float mvf = (float)__builtin_bit_cast(
                        bf16_t, (ushort)(mvCur[mf][cf >> 1][(cf & 1) * 4 + r]));
                    const float pm = p[mf][cf][r] * mvf;
                    const bf16_t h = (bf16_t)pm;
                    const bf16_t l = (bf16_t)(pm - (float)h);
                    phi[mf][kc2][j] = __builtin_bit_cast(short, h);
                    plo[mf][kc2][j] = __builtin_bit_cast(short, l);
                }

        __syncthreads();  // barrier A: drains vmcnt -> V(t), K(t+1), mask ready

        // ---- PV (swapped): each V fragment feeds BOTH mf fragments
        __builtin_amdgcn_s_setprio(1);
#pragma unroll
        for (int kc2 = 0; kc2 < 2; kc2++) {
#pragma unroll
            for (int df = 0; df < 4; df++) {
                const int fi = df * 2 + kc2;
                const short8 vh = ld8(&VsH[(fi * 64 + lane) * 8]);
                const short8 vl = ld8(&VsL[(fi * 64 + lane) * 8]);
#pragma unroll
                for (int mf = 0; mf < 2; mf++) {
                    acco[mf][df] = mfma_bf16(vh, phi[mf][kc2], acco[mf][df]);
                    acco[mf][df] = mfma_bf16(vl, phi[mf][kc2], acco[mf][df]);
                    acco[mf][df] = mfma_bf16(vh, plo[mf][kc2], acco[mf][df]);
                }
            }
        }
        __builtin_amdgcn_s_setprio(0);

        __syncthreads();  // barrier B: all waves done reading Vs before next STAGE_V
#pragma unroll
        for (int mf = 0; mf < 2; mf++)
#pragma unroll
            for (int hh = 0; hh < 2; hh++) mvCur[mf][hh] = mvNxt[mf][hh];
        cur ^= 1;
    }
#undef STAGE_K
#undef STAGE_V

    // ---- epilogue: normalize (per-lane), split hi/lo, store O as [B,S,D]
    const int b = bh >> 4, hh = bh & (NH - 1);
#pragma unroll
    for (int mf = 0; mf < 2; mf++) {
        const float inv = 1.0f / lrun[mf];
        const size_t obase = ((size_t)b * S_LEN + qrow0 + mf * 16) * DMODEL + hh * HD;
#pragma unroll
        for (int df = 0; df < 4; df++) {
#pragma unroll
            for (int r = 0; r < 4; r++) {
                const int d = df * 16 + fg * 4 + r;
                const float o = acco[mf][df][r] * inv;
                const bf16_t h = (bf16_t)o;
                Ohi[obase + d] = h;
                Olo[obase + d] = (bf16_t)(o - (float)h);
            }
        }
    }
}

// ---------------------------------------------------------------------------
extern "C" void kernel_launch(void* const* d_in, const int* in_sizes, int n_in,
                              void* d_out, int out_size, void* d_ws, size_t ws_size,
                              hipStream_t stream) {
    (void)in_sizes; (void)n_in; (void)out_size;
    if (ws_size < WS_REQUIRED) return;  // clean incorrect-output signal, not an OOB crash

    const float* q    = (const float*)d_in[0];
    const float* k    = (const float*)d_in[1];
    const float* v    = (const float*)d_in[2];
    const int*   mask = (const int*)  d_in[3];
    const float* wq   = (const float*)d_in[4];
    const float* wk   = (const float*)d_in[5];
    const float* wv   = (const float*)d_in[6];
    const float* wout = (const float*)d_in[7];
    char* ws = (char*)d_ws;
    float* out = (float*)d_out;

    const size_t nX = (size_t)BATCH * S_LEN * DMODEL;  // 4,194,304
    const size_t nW = (size_t)DMODEL * DMODEL;         // 1,048,576
    const size_t nM = (size_t)S_LEN * S_LEN;           // 4,194,304
    const dim3 blk(256);

    // fp32 -> hi/lo splits
    cvt_split_kernel<<<dim3(nX / 1024), blk, 0, stream>>>(q, (bf16_t*)(ws + OFF_XHI(0)), (bf16_t*)(ws + OFF_XLO(0)), (int)nX);
    cvt_split_kernel<<<dim3(nX / 1024), blk, 0, stream>>>(k, (bf16_t*)(ws + OFF_XHI(1)), (bf16_t*)(ws + OFF_XLO(1)), (int)nX);
    cvt_split_kernel<<<dim3(nX / 1024), blk, 0, stream>>>(v, (bf16_t*)(ws + OFF_XHI(2)), (bf16_t*)(ws + OFF_XLO(2)), (int)nX);
    cvt_split_kernel<<<dim3(nW / 1024), blk, 0, stream>>>(wq,   (bf16_t*)(ws + OFF_WHI(0)), (bf16_t*)(ws + OFF_WLO(0)), (int)nW);
    cvt_split_kernel<<<dim3(nW / 1024), blk, 0, stream>>>(wk,   (bf16_t*)(ws + OFF_WHI(1)), (bf16_t*)(ws + OFF_WLO(1)), (int)nW);
    cvt_split_kernel<<<dim3(nW / 1024), blk, 0, stream>>>(wv,   (bf16_t*)(ws + OFF_WHI(2)), (bf16_t*)(ws + OFF_WLO(2)), (int)nW);
    cvt_split_kernel<<<dim3(nW / 1024), blk, 0, stream>>>(wout, (bf16_t*)(ws + OFF_WHI(3)), (bf16_t*)(ws + OFF_WLO(3)), (int)nW);

    // q/k/v projections (z = 0/1/2), head-split epilogues
    gemm_split_kernel<0><<<dim3(32, 8, 3), blk, 0, stream>>>(ws, nullptr);

    // mask -> bf16 {0,1} into region freed by the input splits
    cvt_mask_kernel<<<dim3(nM / 1024), blk, 0, stream>>>(mask, (bf16_t*)(ws + OFF_MASKB), (int)nM);

    // flash attention (512 blocks, mf=2: 32 q-rows per wave)
    attn_kernel<<<dim3(S_LEN / 128, BATCH * NH), blk, 0, stream>>>(ws);

    // output projection -> d_out (fp32)
    gemm_split_kernel<1><<<dim3(32, 8, 1), blk, 0, stream>>>(ws, out);
}

// Round 11
// 411.223 us; speedup vs baseline: 1.8994x; 1.0197x over previous
//
#include <hip/hip_runtime.h>
#include <stdint.h>

// ---------------------------------------------------------------------------
// MHA forward, MI355X/gfx950.
// Reference: proj(q,k,v) -> scores=QK^T/8 -> softmax (FULL row) -> mask-fill
// (post-softmax, -1e-9 where mask==0) -> PV -> out @ wout^T.   All fp32.
//
// Split-bf16 (hi/lo) MFMA everywhere: a*b ~= ahi*bhi + ahi*blo + alo*bhi.
// The -1e-9 masked-fill value is approximated by 0 (contribution ~3e-8 abs).
//
// R11 (attn now 150us; non-attn ~270us dominates.  Proj/outproj GEMM still
//      serial stage->sync->compute -- full latency exposed per K-step):
//  1. GEMM double-buffered prefetch (R8-attn pattern): issue STAGE(ks+32,
//     buf^1) BEFORE frag reads + 48 MFMA from buf[cur]; single sync per
//     K-step whose vmcnt drain lands after compute.  64KB LDS.
//  2. Launch fusion: qkv cvt -> 1 kernel (grid.y=3), weight cvts -> 1
//     kernel (grid.y=4).  10 dispatches -> 6.
//  attn unchanged from R10 (mf=2, 149.5us).
// ---------------------------------------------------------------------------

#define BATCH  2
#define S_LEN  2048
#define DMODEL 1024
#define NH     16
#define HD     64

typedef __bf16 bf16_t;
typedef short  short8 __attribute__((ext_vector_type(8)));   // 8 x bf16 bits
typedef float  f32x4  __attribute__((ext_vector_type(4)));

#define AS1 __attribute__((address_space(1)))
#define AS3 __attribute__((address_space(3)))

static constexpr size_t MB = (size_t)1 << 20;
static constexpr size_t WS_REQUIRED = 112 * MB;
// Workspace layout (byte offsets). High-water: 112 MB.
//  0..48MB   : input splits qx/kx/vx (hi,lo)   [dead after projections]
//  0..16MB   : (reused) attention output O hi/lo  [written by attn]
//  16..24MB  : (reused) mask as bf16 {0,1}        [written after projections]
//  48..64MB  : weight splits wq,wk,wv,wout (hi,lo)
//  64..112MB : Q (pre-scaled log2e/8), K as [B,H,S,hd]; V^T [B,H,hd,S]
#define OFF_XHI(z)  ((size_t)(z) * 16 * MB)
#define OFF_XLO(z)  (OFF_XHI(z) + 8 * MB)
#define OFF_WHI(z)  (48 * MB + (size_t)(z) * 4 * MB)
#define OFF_WLO(z)  (OFF_WHI(z) + 2 * MB)
#define OFF_PHI(z)  (64 * MB + (size_t)(z) * 16 * MB)   // z=0:Q 1:K 2:VT
#define OFF_PLO(z)  (OFF_PHI(z) + 8 * MB)
#define OFF_OHI     ((size_t)0)
#define OFF_OLO     (8 * MB)
#define OFF_MASKB   (16 * MB)

__device__ __forceinline__ f32x4 mfma_bf16(short8 a, short8 b, f32x4 c) {
    return __builtin_amdgcn_mfma_f32_16x16x32_bf16(a, b, c, 0, 0, 0);
}

__device__ __forceinline__ short8 ld8(const bf16_t* p) {
    return *reinterpret_cast<const short8*>(p);
}

// ---------------------------------------------------------------------------
// fp32 -> (bf16 hi, bf16 lo) splits.  qkv: grid.y selects q/k/v (size nX).
// w: grid.y selects wq/wk/wv/wout (size nW).
// ---------------------------------------------------------------------------
__device__ __forceinline__ void cvt_split_body(const float* __restrict__ x,
                                               bf16_t* __restrict__ hi,
                                               bf16_t* __restrict__ lo) {
    const int i = (blockIdx.x * blockDim.x + threadIdx.x) * 4;
    const float4 v = *reinterpret_cast<const float4*>(x + i);
    float s[4] = {v.x, v.y, v.z, v.w};
    ushort hbits[4], lbits[4];
#pragma unroll
    for (int j = 0; j < 4; j++) {
        bf16_t hh = (bf16_t)s[j];
        bf16_t ll = (bf16_t)(s[j] - (float)hh);
        hbits[j] = __builtin_bit_cast(ushort, hh);
        lbits[j] = __builtin_bit_cast(ushort, ll);
    }
    *reinterpret_cast<ushort4*>(hi + i) = ushort4{hbits[0], hbits[1], hbits[2], hbits[3]};
    *reinterpret_cast<ushort4*>(lo + i) = ushort4{lbits[0], lbits[1], lbits[2], lbits[3]};
}

__global__ void cvt_qkv_kernel(const float* __restrict__ q, const float* __restrict__ k,
                               const float* __restrict__ v, char* __restrict__ ws) {
    const int z = blockIdx.y;
    const float* src = (z == 0) ? q : (z == 1) ? k : v;
    cvt_split_body(src, (bf16_t*)(ws + OFF_XHI(z)), (bf16_t*)(ws + OFF_XLO(z)));
}

__global__ void cvt_w_kernel(const float* __restrict__ wq, const float* __restrict__ wk,
                             const float* __restrict__ wv, const float* __restrict__ wout,
                             char* __restrict__ ws) {
    const int z = blockIdx.y;
    const float* src = (z == 0) ? wq : (z == 1) ? wk : (z == 2) ? wv : wout;
    cvt_split_body(src, (bf16_t*)(ws + OFF_WHI(z)), (bf16_t*)(ws + OFF_WLO(z)));
}

// mask int32 -> bf16 {0,1}
__global__ void cvt_mask_kernel(const int* __restrict__ m, bf16_t* __restrict__ mb, int n) {
    int i = (blockIdx.x * blockDim.x + threadIdx.x) * 4;
    if (i >= n) return;
    const int4 v = *reinterpret_cast<const int4*>(m + i);
    int s[4] = {v.x, v.y, v.z, v.w};
    ushort b[4];
#pragma unroll
    for (int j = 0; j < 4; j++) {
        bf16_t t = (bf16_t)(s[j] ? 1.0f : 0.0f);
        b[j] = __builtin_bit_cast(ushort, t);
    }
    *reinterpret_cast<ushort4*>(mb + i) = ushort4{b[0], b[1], b[2], b[3]};
}

// ---------------------------------------------------------------------------
// Split-bf16 GEMM, C = A @ B^T (both operands K-contiguous).  128x128 tile,
// BK=32, 256 threads = 4 waves (2x2), each wave 64x64 = 4x4 16x16x32 frags.
// DOUBLE-BUFFERED: per K-step issue STAGE(ks+32, buf^1) first, then frag
// reads + 48 MFMA from buf[cur], then one sync (vmcnt drain after compute).
// FINAL=0: grid.z picks q/k/v; epilogue head-splits (Q scaled log2e/8;
// V transposed).  FINAL=1: output projection -> d_out fp32.
// ---------------------------------------------------------------------------
template <int FINAL>
__global__ __launch_bounds__(256, 2) void gemm_split_kernel(char* __restrict__ ws,
                                                            float* __restrict__ fout) {
    __shared__ __align__(16) bf16_t AsH[2][128 * 32];
    __shared__ __align__(16) bf16_t AsL[2][128 * 32];
    __shared__ __align__(16) bf16_t BsH[2][128 * 32];
    __shared__ __align__(16) bf16_t BsL[2][128 * 32];

    const int z = FINAL ? 3 : blockIdx.z;
    const bf16_t* Ahi = FINAL ? (const bf16_t*)(ws + OFF_OHI) : (const bf16_t*)(ws + OFF_XHI(z));
    const bf16_t* Alo = FINAL ? (const bf16_t*)(ws + OFF_OLO) : (const bf16_t*)(ws + OFF_XLO(z));
    const bf16_t* Bhi = (const bf16_t*)(ws + OFF_WHI(z));
    const bf16_t* Blo = (const bf16_t*)(ws + OFF_WLO(z));
    bf16_t* Ohi = FINAL ? nullptr : (bf16_t*)(ws + OFF_PHI(z));
    bf16_t* Olo = FINAL ? nullptr : (bf16_t*)(ws + OFF_PLO(z));
    // z==0: fold 1/sqrt(hd) AND log2(e) into Q (softmax runs in exp2 domain)
    const float scale = (!FINAL && z == 0) ? 0.18033688011112042f : 1.0f;

    const int tid = threadIdx.x;
    const int lane = tid & 63, w = tid >> 6;
    const int wr = w >> 1, wc = w & 1;
    const int fr = lane & 15, fg = lane >> 4;
    const int m0 = blockIdx.x * 128, n0 = blockIdx.y * 128;
    const int K = 1024;

    f32x4 acc[4][4];
#pragma unroll
    for (int i = 0; i < 4; i++)
#pragma unroll
        for (int j = 0; j < 4; j++) acc[i][j] = f32x4{0.f, 0.f, 0.f, 0.f};

    // per-thread staging geometry (chunk c = i*256+tid covers 16B)
    size_t gAoff[2], gBoff[2], ldst[2];
#pragma unroll
    for (int i = 0; i < 2; i++) {
        const int c = i * 256 + tid;
        const int row = c >> 2;
        const int ce = (c & 3) * 8;
        gAoff[i] = (size_t)(m0 + row) * K + ce;   // + ks
        gBoff[i] = (size_t)(n0 + row) * K + ce;   // + ks
        ldst[i] = (size_t)(i * 256 + w * 64) * 8;
    }

#define GSTAGE(KS, BUF)                                                                            \
    {                                                                                              \
        _Pragma("unroll") for (int i = 0; i < 2; i++) {                                            \
            const size_t gA = gAoff[i] + (KS);                                                     \
            const size_t gB = gBoff[i] + (KS);                                                     \
            __builtin_amdgcn_global_load_lds((const AS1 void*)(Ahi + gA),                          \
                                             (AS3 void*)((AS3 bf16_t*)AsH[BUF] + ldst[i]), 16, 0, 0); \
            __builtin_amdgcn_global_load_lds((const AS1 void*)(Alo + gA),                          \
                                             (AS3 void*)((AS3 bf16_t*)AsL[BUF] + ldst[i]), 16, 0, 0); \
            __builtin_amdgcn_global_load_lds((const AS1 void*)(Bhi + gB),                          \
                                             (AS3 void*)((AS3 bf16_t*)BsH[BUF] + ldst[i]), 16, 0, 0); \
            __builtin_amdgcn_global_load_lds((const AS1 void*)(Blo + gB),                          \
                                             (AS3 void*)((AS3 bf16_t*)BsL[BUF] + ldst[i]), 16, 0, 0); \
        }                                                                                          \
    }

    GSTAGE(0, 0)
    __syncthreads();  // tile-0 staging complete

    int cur = 0;
#pragma unroll 1
    for (int ks = 0; ks < K; ks += 32) {
        if (ks + 32 < K) GSTAGE(ks + 32, cur ^ 1)   // overlaps compute below

        short8 afh[4], afl[4], bfh[4], bfl[4];
#pragma unroll
        for (int i = 0; i < 4; i++) {
            const int ao = (wr * 64 + i * 16 + fr) * 32 + fg * 8;
            const int bo = (wc * 64 + i * 16 + fr) * 32 + fg * 8;
            afh[i] = ld8(&AsH[cur][ao]);
            afl[i] = ld8(&AsL[cur][ao]);
            bfh[i] = ld8(&BsH[cur][bo]);
            bfl[i] = ld8(&BsL[cur][bo]);
        }
        __builtin_amdgcn_s_setprio(1);
#pragma unroll
        for (int i = 0; i < 4; i++)
#pragma unroll
            for (int j = 0; j < 4; j++) {
                acc[i][j] = mfma_bf16(afh[i], bfh[j], acc[i][j]);
                acc[i][j] = mfma_bf16(afh[i], bfl[j], acc[i][j]);
                acc[i][j] = mfma_bf16(afl[i], bfh[j], acc[i][j]);
            }
        __builtin_amdgcn_s_setprio(0);

        __syncthreads();  // drains vmcnt (next tile staged); buf[cur] reads done
        cur ^= 1;
    }
#undef GSTAGE

    // Epilogue. C/D frag: col = lane&15, row = (lane>>4)*4 + reg  [HW-verified]
#pragma unroll
    for (int i = 0; i < 4; i++) {
#pragma unroll
        for (int j = 0; j < 4; j++) {
            const int ncol = n0 + wc * 64 + j * 16 + fr;
#pragma unroll
            for (int r = 0; r < 4; r++) {
                const int m = m0 + wr * 64 + i * 16 + fg * 4 + r;
                const float val = acc[i][j][r] * scale;
                if (FINAL) {
                    fout[(size_t)m * DMODEL + ncol] = val;
                } else {
                    const bf16_t h = (bf16_t)val;
                    const bf16_t l = (bf16_t)(val - (float)h);
                    const int b = m >> 11, s = m & (S_LEN - 1);
                    const int hh = ncol >> 6, d = ncol & (HD - 1);
                    size_t idx;
                    if (z == 2) idx = ((size_t)(b * NH + hh) * HD + d) * S_LEN + s;      // VT [B,H,hd,S]
                    else        idx = ((size_t)(b * NH + hh) * S_LEN + s) * HD + d;      // [B,H,S,hd]
                    Ohi[idx] = h;
                    Olo[idx] = l;
                }
            }
        }
    }
}

// ---------------------------------------------------------------------------
// Flash attention, swapped-operand, mf=2 (32 q-rows/wave).  K dbuf + V
// single buf (48KB LDS).  Grid: (S/128, B*H), 256 thr = 4 waves; lane
// (fr,fg) owns q-rows q0 + w*32 + {0,16} + fr.   [unchanged from R10]
// ---------------------------------------------------------------------------
__global__ __launch_bounds__(256, 2) void attn_kernel(char* __restrict__ ws) {
    __shared__ __align__(16) bf16_t KsH[2][8 * 64 * 8];   // 2 x 8KB
    __shared__ __align__(16) bf16_t KsL[2][8 * 64 * 8];   // 2 x 8KB
    __shared__ __align__(16) bf16_t VsH[8 * 64 * 8];      // 8KB
    __shared__ __align__(16) bf16_t VsL[8 * 64 * 8];      // 8KB

    const bf16_t* Qhi = (const bf16_t*)(ws + OFF_PHI(0));
    const bf16_t* Qlo = (const bf16_t*)(ws + OFF_PLO(0));
    const bf16_t* Khi = (const bf16_t*)(ws + OFF_PHI(1));
    const bf16_t* Klo = (const bf16_t*)(ws + OFF_PLO(1));
    const bf16_t* Vhi = (const bf16_t*)(ws + OFF_PHI(2));
    const bf16_t* Vlo = (const bf16_t*)(ws + OFF_PLO(2));
    const bf16_t* Mb  = (const bf16_t*)(ws + OFF_MASKB);
    bf16_t* Ohi = (bf16_t*)(ws + OFF_OHI);
    bf16_t* Olo = (bf16_t*)(ws + OFF_OLO);

    const int tid = threadIdx.x, lane = tid & 63, w = tid >> 6;
    const int fr = lane & 15, fg = lane >> 4;
    const int bh = blockIdx.y;
    const int q0 = blockIdx.x * 128;
    const int qrow0 = q0 + w * 32 + fr;         // mf row = qrow0 + mf*16
    const size_t qkBase = (size_t)bh * S_LEN * HD;
    const size_t vtBase = (size_t)bh * HD * S_LEN;

    size_t kSrc[2], vSrc[2];
#pragma unroll
    for (int i = 0; i < 2; i++) {
        const int s = i * 256 + tid;
        const int l = s & 63, f = (s >> 6) & 7;
        const int sfr = l & 15, sfg = l >> 4;
        const int cf = f >> 1, kc = f & 1;
        const int r = (cf & 1) * 4 + (sfr & 3) + (sfr >> 2) * 8 + (cf >> 1) * 32;
        kSrc[i] = qkBase + (size_t)r * HD + kc * 32 + sfg * 8;          // + k0*HD
        vSrc[i] = vtBase + (size_t)((f >> 1) * 16 + sfr) * S_LEN + (f & 1) * 32 + sfg * 8;  // + k0
    }

    short8 qh[2][2], ql[2][2];
#pragma unroll
    for (int mf = 0; mf < 2; mf++)
#pragma unroll
        for (int kc = 0; kc < 2; kc++) {
            const size_t off = qkBase + (size_t)(qrow0 + mf * 16) * HD + kc * 32 + fg * 8;
            qh[mf][kc] = ld8(Qhi + off);
            ql[mf][kc] = ld8(Qlo + off);
        }

    f32x4 acco[2][4];
#pragma unroll
    for (int mf = 0; mf < 2; mf++)
#pragma unroll
        for (int df = 0; df < 4; df++) acco[mf][df] = f32x4{0.f, 0.f, 0.f, 0.f};
    float mrun[2] = {-__builtin_inff(), -__builtin_inff()};
    float lrun[2] = {0.f, 0.f};

    const size_t mrowBase0 = (size_t)qrow0 * S_LEN;
    const size_t mrowBase1 = (size_t)(qrow0 + 16) * S_LEN;

#define STAGE_K(K0, BUF)                                                                           \
    {                                                                                              \
        _Pragma("unroll") for (int i = 0; i < 2; i++) {                                            \
            const size_t ko = kSrc[i] + (size_t)(K0) * HD;                                         \
            const size_t dst = (size_t)(i * 256 + w * 64) * 8;                                     \
            __builtin_amdgcn_global_load_lds((const AS1 void*)(Khi + ko),                          \
                                             (AS3 void*)((AS3 bf16_t*)KsH[BUF] + dst), 16, 0, 0);  \
            __builtin_amdgcn_global_load_lds((const AS1 void*)(Klo + ko),                          \
                                             (AS3 void*)((AS3 bf16_t*)KsL[BUF] + dst), 16, 0, 0);  \
        }                                                                                          \
    }
#define STAGE_V(K0)                                                                                \
    {                                                                                              \
        _Pragma("unroll") for (int i = 0; i < 2; i++) {                                            \
            const size_t vo = vSrc[i] + (K0);                                                      \
            const size_t dst = (size_t)(i * 256 + w * 64) * 8;                                     \
            __builtin_amdgcn_global_load_lds((const AS1 void*)(Vhi + vo),                          \
                                             (AS3 void*)((AS3 bf16_t*)VsH + dst), 16, 0, 0);       \
            __builtin_amdgcn_global_load_lds((const AS1 void*)(Vlo + vo),                          \
                                             (AS3 void*)((AS3 bf16_t*)VsL + dst), 16, 0, 0);       \
        }                                                                                          \
    }

    // ---- prologue: stage K(0), prefetch mask(0) for both mf rows
    STAGE_K(0, 0)
    short8 mvCur[2][2], mvNxt[2][2];
    mvCur[0][0] = ld8(Mb + mrowBase0 + fg * 8);
    mvCur[0][1] = ld8(Mb + mrowBase0 + 32 + fg * 8);
    mvCur[1][0] = ld8(Mb + mrowBase1 + fg * 8);
    mvCur[1][1] = ld8(Mb + mrowBase1 + 32 + fg * 8);
#pragma unroll
    for (int mf = 0; mf < 2; mf++)
#pragma unroll
        for (int hh = 0; hh < 2; hh++) mvNxt[mf][hh] = mvCur[mf][hh];
    __syncthreads();  // K(0) + mask(0) complete

    int cur = 0;
#pragma unroll 1
    for (int k0 = 0; k0 < S_LEN; k0 += 64) {
        // ---- issue V(t), K(t+1), mask(t+1) (overlap QK^T + softmax below)
        STAGE_V(k0)
        if (k0 + 64 < S_LEN) {
            STAGE_K(k0 + 64, cur ^ 1)
            mvNxt[0][0] = ld8(Mb + mrowBase0 + (k0 + 64) + fg * 8);
            mvNxt[0][1] = ld8(Mb + mrowBase0 + (k0 + 64) + 32 + fg * 8);
            mvNxt[1][0] = ld8(Mb + mrowBase1 + (k0 + 64) + fg * 8);
            mvNxt[1][1] = ld8(Mb + mrowBase1 + (k0 + 64) + 32 + fg * 8);
        }

        // ---- scores (swapped): each K fragment feeds BOTH mf fragments
        f32x4 sacc[2][4];
#pragma unroll
        for (int mf = 0; mf < 2; mf++)
#pragma unroll
            for (int cf = 0; cf < 4; cf++) sacc[mf][cf] = f32x4{0.f, 0.f, 0.f, 0.f};
        __builtin_amdgcn_s_setprio(1);
#pragma unroll
        for (int cf = 0; cf < 4; cf++) {
#pragma unroll
            for (int kc = 0; kc < 2; kc++) {
                const int fi = cf * 2 + kc;
                const short8 kh = ld8(&KsH[cur][(fi * 64 + lane) * 8]);
                const short8 kl = ld8(&KsL[cur][(fi * 64 + lane) * 8]);
#pragma unroll
                for (int mf = 0; mf < 2; mf++) {
                    sacc[mf][cf] = mfma_bf16(kh, qh[mf][kc], sacc[mf][cf]);
                    sacc[mf][cf] = mfma_bf16(kl, qh[mf][kc], sacc[mf][cf]);
                    sacc[mf][cf] = mfma_bf16(kh, ql[mf][kc], sacc[mf][cf]);
                }
            }
        }
        __builtin_amdgcn_s_setprio(0);

        // ---- online softmax (exp2 domain) per mf, in-lane + 2 shfls, defer-max
        float p[2][4][4];
#pragma unroll
        for (int mf = 0; mf < 2; mf++) {
            float mx = sacc[mf][0][0];
#pragma unroll
            for (int cf = 0; cf < 4; cf++)
#pragma unroll
                for (int r = 0; r < 4; r++) mx = fmaxf(mx, sacc[mf][cf][r]);
            mx = fmaxf(mx, __shfl_xor(mx, 16, 64));
            mx = fmaxf(mx, __shfl_xor(mx, 32, 64));
            if (!__all(mx <= mrun[mf] + 8.0f)) {  // rescale only when needed
                const float mnew = fmaxf(mrun[mf], mx);
                const float alpha = exp2f(mrun[mf] - mnew);
                mrun[mf] = mnew;
                lrun[mf] *= alpha;
#pragma unroll
                for (int df = 0; df < 4; df++) acco[mf][df] *= alpha;
            }
            float psum = 0.f;
#pragma unroll
            for (int cf = 0; cf < 4; cf++)
#pragma unroll
                for (int r = 0; r < 4; r++) {
                    p[mf][cf][r] = exp2f(sacc[mf][cf][r] - mrun[mf]);
                    psum += p[mf][cf][r];
                }
            psum += __shfl_xor(psum, 16, 64);
            psum += __shfl_xor(psum, 32, 64);
            lrun[mf] += psum;
        }

        // ---- masked P -> hi/lo PV B-fragments, pure in-register
        short8 phi[2][2], plo[2][2];
#pragma unroll
        for (int mf = 0; mf < 2; mf++)
#pragma unroll
            for (int kc2 = 0; kc2 < 2; kc2++)
#pragma unroll
                for (int j = 0; j < 8; j++) {
                    const int cf = kc2 * 2 + (j >> 2), r = j & 3;
                    const float mvf = (float)__builtin_bit_cast(
                        bf16_t, (ushort)(mvCur[mf][cf >> 1][(cf & 1) * 4 + r]));
                    const float pm = p[mf][cf][r] * mvf;
                    const bf16_t h = (bf16_t)pm;
                    const bf16_t l = (bf16_t)(pm - (float)h);
                    phi[mf][kc2][j] = __builtin_bit_cast(short, h);
                    plo[mf][kc2][j] = __builtin_bit_cast(short, l);
                }

        __syncthreads();  // barrier A: drains vmcnt -> V(t), K(t+1), mask ready

        // ---- PV (swapped): each V fragment feeds BOTH mf fragments
        __builtin_amdgcn_s_setprio(1);
#pragma unroll
        for (int kc2 = 0; kc2 < 2; kc2++) {
#pragma unroll
            for (int df = 0; df < 4; df++) {
                const int fi = df * 2 + kc2;
                const short8 vh = ld8(&VsH[(fi * 64 + lane) * 8]);
                const short8 vl = ld8(&VsL[(fi * 64 + lane) * 8]);
#pragma unroll
                for (int mf = 0; mf < 2; mf++) {
                    acco[mf][df] = mfma_bf16(vh, phi[mf][kc2], acco[mf][df]);
                    acco[mf][df] = mfma_bf16(vl, phi[mf][kc2], acco[mf][df]);
                    acco[mf][df] = mfma_bf16(vh, plo[mf][kc2], acco[mf][df]);
                }
            }
        }
        __builtin_amdgcn_s_setprio(0);

        __syncthreads();  // barrier B: all waves done reading Vs before next STAGE_V
#pragma unroll
        for (int mf = 0; mf < 2; mf++)
#pragma unroll
            for (int hh = 0; hh < 2; hh++) mvCur[mf][hh] = mvNxt[mf][hh];
        cur ^= 1;
    }
#undef STAGE_K
#undef STAGE_V

    // ---- epilogue: normalize (per-lane), split hi/lo, store O as [B,S,D]
    const int b = bh >> 4, hh = bh & (NH - 1);
#pragma unroll
    for (int mf = 0; mf < 2; mf++) {
        const float inv = 1.0f / lrun[mf];
        const size_t obase = ((size_t)b * S_LEN + qrow0 + mf * 16) * DMODEL + hh * HD;
#pragma unroll
        for (int df = 0; df < 4; df++) {
#pragma unroll
            for (int r = 0; r < 4; r++) {
                const int d = df * 16 + fg * 4 + r;
                const float o = acco[mf][df][r] * inv;
                const bf16_t h = (bf16_t)o;
                Ohi[obase + d] = h;
                Olo[obase + d] = (bf16_t)(o - (float)h);
            }
        }
    }
}

// ---------------------------------------------------------------------------
extern "C" void kernel_launch(void* const* d_in, const int* in_sizes, int n_in,
                              void* d_out, int out_size, void* d_ws, size_t ws_size,
                              hipStream_t stream) {
    (void)in_sizes; (void)n_in; (void)out_size;
    if (ws_size < WS_REQUIRED) return;  // clean incorrect-output signal, not an OOB crash

    const float* q    = (const float*)d_in[0];
    const float* k    = (const float*)d_in[1];
    const float* v    = (const float*)d_in[2];
    const int*   mask = (const int*)  d_in[3];
    const float* wq   = (const float*)d_in[4];
    const float* wk   = (const float*)d_in[5];
    const float* wv   = (const float*)d_in[6];
    const float* wout = (const float*)d_in[7];
    char* ws = (char*)d_ws;
    float* out = (float*)d_out;

    const size_t nX = (size_t)BATCH * S_LEN * DMODEL;  // 4,194,304
    const size_t nW = (size_t)DMODEL * DMODEL;         // 1,048,576
    const size_t nM = (size_t)S_LEN * S_LEN;           // 4,194,304
    const dim3 blk(256);

    // fp32 -> hi/lo splits (fused: 2 launches instead of 7)
    cvt_qkv_kernel<<<dim3(nX / 1024, 3), blk, 0, stream>>>(q, k, v, ws);
    cvt_w_kernel<<<dim3(nW / 1024, 4), blk, 0, stream>>>(wq, wk, wv, wout, ws);

    // q/k/v projections (z = 0/1/2), head-split epilogues
    gemm_split_kernel<0><<<dim3(32, 8, 3), blk, 0, stream>>>(ws, nullptr);

    // mask -> bf16 {0,1} into region freed by the input splits
    cvt_mask_kernel<<<dim3(nM / 1024), blk, 0, stream>>>(mask, (bf16_t*)(ws + OFF_MASKB), (int)nM);

    // flash attention (512 blocks, mf=2: 32 q-rows per wave)
    attn_kernel<<<dim3(S_LEN / 128, BATCH * NH), blk, 0, stream>>>(ws);

    // output projection -> d_out (fp32)
    gemm_split_kernel<1><<<dim3(32, 8, 1), blk, 0, stream>>>(ws, out);
}